// Round 1
// baseline (3129.508 us; speedup 1.0000x reference)
//
#include <hip/hip_runtime.h>
#include <hip/hip_bf16.h>

// ---------------------------------------------------------------------------
// DeepConvWeigthNet on MI355X, fp32 direct implementation.
// Pipeline:
//   conv1(3->32)+PReLU -> bodyA
//   per batch: conv2(32->64)+PReLU -> tmp64 ; conv3(64->32)+PReLU -> bodyA
//   per head i: headconv(32->5)->y (+ global sums via atomics)
//               z = sigmoid(ca2 @ relu(ca1 @ mean))        (tiny kernel)
//               hpass: separable horizontal box sums (5/15/25) of stage input
//               combine: vertical box sums + sharpen + inline channel softmax
// Workspace: 128 MiB (bodyA) + 80 MiB (reused region) + 1 KiB  ~= 209 MiB.
// ---------------------------------------------------------------------------

__global__ void zero_k(float* __restrict__ p, int n) {
  int i = blockIdx.x * blockDim.x + threadIdx.x;
  if (i < n) p[i] = 0.f;
}

// Direct 3x3 conv (cross-correlation, zero pad 1), NCHW.
// Block: 256 threads = 32x8, each thread computes PY vertical pixels x COB ocs.
template<int CIN, int ICB, int COB, int PY, bool PRELU, bool HEADSUM>
__global__ __launch_bounds__(256)
void conv3x3_k(const float* __restrict__ in, const float* __restrict__ wgt,
               const float* __restrict__ bias, const float* __restrict__ alpha_p,
               float* __restrict__ out, float* __restrict__ sums,
               int Cout, int H, int W, int nOcG)
{
  constexpr int TH = 8 * PY;        // tile height in output rows
  constexpr int ROWE = 34;          // 32 + 2 halo
  __shared__ float s_in[ICB][TH + 2][ROWE];
  __shared__ float s_w[COB][ICB][12];   // 9 weights padded to 12 -> 16B aligned

  const int tid = threadIdx.x;
  const int tx = tid & 31, ty = tid >> 5;
  const int g = blockIdx.z % nOcG, b = blockIdx.z / nOcG;
  const int x0 = blockIdx.x * 32, y0 = blockIdx.y * TH;
  const int oc0 = g * COB;
  const float* inb = in + (size_t)b * CIN * H * W;

  float acc[PY][COB];
#pragma unroll
  for (int p = 0; p < PY; ++p)
#pragma unroll
    for (int o = 0; o < COB; ++o) acc[p][o] = 0.f;

  const int yb = ty * PY;

  for (int ic0 = 0; ic0 < CIN; ic0 += ICB) {
    constexpr int TILE = ICB * (TH + 2) * ROWE;
    for (int idx = tid; idx < TILE; idx += 256) {
      int icl = idx / ((TH + 2) * ROWE);
      int rem = idx - icl * ((TH + 2) * ROWE);
      int yy = rem / ROWE;
      int xx = rem - yy * ROWE;
      int gy = y0 + yy - 1, gx = x0 + xx - 1;
      float v = 0.f;
      if ((unsigned)gy < (unsigned)H && (unsigned)gx < (unsigned)W)
        v = inb[(size_t)(ic0 + icl) * H * W + (size_t)gy * W + gx];
      s_in[icl][yy][xx] = v;
    }
    for (int idx = tid; idx < COB * ICB * 9; idx += 256) {
      int oc = idx / (ICB * 9);
      int rem = idx - oc * (ICB * 9);
      int icl = rem / 9, k = rem - icl * 9;
      s_w[oc][icl][k] = wgt[((size_t)(oc0 + oc) * CIN + (ic0 + icl)) * 9 + k];
    }
    __syncthreads();

#pragma unroll 1
    for (int icl = 0; icl < ICB; ++icl) {
      float iv[PY + 2][3];
#pragma unroll
      for (int j = 0; j < PY + 2; ++j)
#pragma unroll
        for (int kx = 0; kx < 3; ++kx)
          iv[j][kx] = s_in[icl][yb + j][tx + kx];
#pragma unroll
      for (int o = 0; o < COB; ++o) {
        float w9[9];
#pragma unroll
        for (int k = 0; k < 9; ++k) w9[k] = s_w[o][icl][k];
#pragma unroll
        for (int p = 0; p < PY; ++p)
#pragma unroll
          for (int ky = 0; ky < 3; ++ky)
#pragma unroll
            for (int kx = 0; kx < 3; ++kx)
              acc[p][o] = fmaf(iv[p + ky][kx], w9[ky * 3 + kx], acc[p][o]);
      }
    }
    __syncthreads();
  }

  float alpha = 0.f;
  if constexpr (PRELU) alpha = alpha_p[0];

#pragma unroll
  for (int o = 0; o < COB; ++o) {
    const float bv = bias[oc0 + o];
    float partial = 0.f;
#pragma unroll
    for (int p = 0; p < PY; ++p) {
      const int gy = y0 + yb + p, gx = x0 + tx;
      if (gy < H && gx < W) {
        float v = acc[p][o] + bv;
        if constexpr (PRELU) v = (v > 0.f) ? v : alpha * v;
        out[(((size_t)b * Cout + oc0 + o) * H + gy) * W + gx] = v;
        if constexpr (HEADSUM) partial += v;
      }
    }
    if constexpr (HEADSUM) {
#pragma unroll
      for (int s = 32; s > 0; s >>= 1) partial += __shfl_down(partial, s, 64);
      if ((tid & 63) == 0) atomicAdd(&sums[(size_t)b * Cout + oc0 + o], partial);
    }
  }
}

// z = sigmoid(ca2 @ relu(ca1 @ mean)) per batch; one thread per batch.
__global__ void head_z_k(const float* __restrict__ sums, const float* __restrict__ caw1,
                         const float* __restrict__ caw2, float* __restrict__ z,
                         int B, float invHW)
{
  int b = threadIdx.x;
  if (b >= B) return;
  float m[5], t[5];
#pragma unroll
  for (int i = 0; i < 5; ++i) m[i] = sums[b * 5 + i] * invHW;
#pragma unroll
  for (int o = 0; o < 5; ++o) {
    float s = 0.f;
#pragma unroll
    for (int i = 0; i < 5; ++i) s = fmaf(caw1[o * 5 + i], m[i], s);
    t[o] = (s > 0.f) ? s : 0.f;
  }
#pragma unroll
  for (int o = 0; o < 5; ++o) {
    float s = 0.f;
#pragma unroll
    for (int i = 0; i < 5; ++i) s = fmaf(caw2[o * 5 + i], t[i], s);
    z[b * 5 + o] = 1.f / (1.f + expf(-s));
  }
}

// Horizontal box sums (widths 5, 15, 25), zero-padded; one block per row.
__global__ __launch_bounds__(256)
void hpass_k(const float* __restrict__ xs, float* __restrict__ h5,
             float* __restrict__ h15, float* __restrict__ h25, int H, int W)
{
  __shared__ float row[512 + 24];      // W <= 512 assumed (W=512 here)
  const int p = blockIdx.y, y = blockIdx.x;
  const size_t off = ((size_t)p * H + y) * W;
  const float* r = xs + off;
  for (int i = threadIdx.x; i < W + 24; i += 256) {
    int gx = i - 12;
    row[i] = ((unsigned)gx < (unsigned)W) ? r[gx] : 0.f;
  }
  __syncthreads();
  for (int x = threadIdx.x; x < W; x += 256) {
    const int c = x + 12;
    float s5 = 0.f;
#pragma unroll
    for (int d = -2; d <= 2; ++d) s5 += row[c + d];
    float s15 = s5;
#pragma unroll
    for (int d = 3; d <= 7; ++d) s15 += row[c + d] + row[c - d];
    float s25 = s15;
#pragma unroll
    for (int d = 8; d <= 12; ++d) s25 += row[c + d] + row[c - d];
    h5[off + x]  = s5;
    h15[off + x] = s15;
    h25[off + x] = s25;
  }
}

// Vertical box sums + sharpen + identity, weighted by inline channel softmax.
__global__ __launch_bounds__(256)
void combine_k(const float* __restrict__ xs, const float* __restrict__ h5,
               const float* __restrict__ h15, const float* __restrict__ h25,
               const float* __restrict__ yhead, const float* __restrict__ z,
               float* __restrict__ out, int H, int W)
{
  const int b = blockIdx.z;
  const int x = blockIdx.x * 32 + (threadIdx.x & 31);
  const int y = blockIdx.y * 8 + (threadIdx.x >> 5);
  if (x >= W || y >= H) return;
  const size_t HW = (size_t)H * W;
  const size_t pix = (size_t)y * W + x;

  // softmax over the 5 head channels (shared across the 3 image channels)
  float sv[5];
  float mx = -1e30f;
#pragma unroll
  for (int c = 0; c < 5; ++c) {
    float v = yhead[((size_t)b * 5 + c) * HW + pix] * z[b * 5 + c];
    sv[c] = v;
    mx = fmaxf(mx, v);
  }
  float se = 0.f;
#pragma unroll
  for (int c = 0; c < 5; ++c) { sv[c] = expf(sv[c] - mx); se += sv[c]; }
  const float inv = 1.f / se;
  const float h0 = sv[0] * inv, h1 = sv[1] * inv, h2 = sv[2] * inv;
  const float h3 = sv[3] * inv, h4 = sv[4] * inv;

#pragma unroll 1
  for (int c = 0; c < 3; ++c) {
    const size_t plane = ((size_t)b * 3 + c) * HW;
    const float* xp = xs + plane;
    float v5 = 0.f, v15 = 0.f, v25 = 0.f;
#pragma unroll
    for (int d = -2; d <= 2; ++d) {
      int yy = y + d;
      if ((unsigned)yy < (unsigned)H) v5 += h5[plane + (size_t)yy * W + x];
    }
#pragma unroll
    for (int d = -7; d <= 7; ++d) {
      int yy = y + d;
      if ((unsigned)yy < (unsigned)H) v15 += h15[plane + (size_t)yy * W + x];
    }
#pragma unroll
    for (int d = -12; d <= 12; ++d) {
      int yy = y + d;
      if ((unsigned)yy < (unsigned)H) v25 += h25[plane + (size_t)yy * W + x];
    }
    const float ctr = xp[pix];
    const float up = (y > 0)     ? xp[pix - W] : 0.f;
    const float dn = (y < H - 1) ? xp[pix + W] : 0.f;
    const float lf = (x > 0)     ? xp[pix - 1] : 0.f;
    const float rt = (x < W - 1) ? xp[pix + 1] : 0.f;
    const float sharp = 5.f * ctr - up - dn - lf - rt;
    out[plane + pix] = h0 * sharp
                     + h1 * ctr
                     + h2 * (v5  * (1.f / 25.f))
                     + h3 * (v15 * (1.f / 225.f))
                     + h4 * (v25 * (1.f / 625.f));
  }
}

extern "C" void kernel_launch(void* const* d_in, const int* in_sizes, int n_in,
                              void* d_out, int out_size, void* d_ws, size_t ws_size,
                              hipStream_t stream)
{
  const float* x   = (const float*)d_in[0];
  const float* w1  = (const float*)d_in[1];
  const float* b1  = (const float*)d_in[2];
  const float* a1  = (const float*)d_in[3];
  const float* w2  = (const float*)d_in[4];
  const float* b2  = (const float*)d_in[5];
  const float* a2  = (const float*)d_in[6];
  const float* w3  = (const float*)d_in[7];
  const float* b3  = (const float*)d_in[8];
  const float* a3  = (const float*)d_in[9];
  const float* hw[3]  = {(const float*)d_in[10], (const float*)d_in[14], (const float*)d_in[18]};
  const float* hb[3]  = {(const float*)d_in[11], (const float*)d_in[15], (const float*)d_in[19]};
  const float* cw1[3] = {(const float*)d_in[12], (const float*)d_in[16], (const float*)d_in[20]};
  const float* cw2[3] = {(const float*)d_in[13], (const float*)d_in[17], (const float*)d_in[21]};
  float* outp = (float*)d_out;

  const int B = 4, H = 512, W = 512;
  const size_t HW = (size_t)H * W;
  const size_t PB = HW * sizeof(float);   // 1 MiB per plane

  // Workspace layout (~209 MiB):
  //   bodyA: B*32 planes (conv1 out, then conv3 out)
  //   r2   : 80 planes, time-multiplexed:
  //          [0..64)  tmp64 (per-batch conv2 out)      -- alive only during conv2/3
  //          [0..20)  ybuf  (head conv out)            -- alive during heads/stages
  //          [20..32) h5  [32..44) h15  [44..56) h25   -- per-stage temps
  //          [56..68) ping  [68..80) pong              -- stage ping-pong
  //   tail : sums (60 f) + z (60 f)
  char* ws = (char*)d_ws;
  float* bodyA  = (float*)ws;
  char*  r2     = ws + (size_t)B * 32 * PB;
  float* tmp64  = (float*)r2;
  float* ybuf   = (float*)r2;
  float* h5buf  = (float*)(r2 + 20 * PB);
  float* h15buf = (float*)(r2 + 32 * PB);
  float* h25buf = (float*)(r2 + 44 * PB);
  float* ping   = (float*)(r2 + 56 * PB);
  float* pong   = (float*)(r2 + 68 * PB);
  float* sums   = (float*)(r2 + 80 * PB);
  float* zbuf   = sums + 64;

  zero_k<<<1, 64, 0, stream>>>(sums, 60);

  // conv1: 3->32 + PReLU (full batch)
  conv3x3_k<3, 3, 16, 2, true, false><<<dim3(16, 32, B * 2), 256, 0, stream>>>(
      x, w1, b1, a1, bodyA, nullptr, 32, H, W, 2);

  // conv2 + conv3 per batch through tmp64 (keeps workspace small)
  for (int b = 0; b < B; ++b) {
    conv3x3_k<32, 4, 16, 4, true, false><<<dim3(16, 16, 4), 256, 0, stream>>>(
        bodyA + (size_t)b * 32 * HW, w2, b2, a2, tmp64, nullptr, 64, H, W, 4);
    conv3x3_k<64, 4, 16, 4, true, false><<<dim3(16, 16, 2), 256, 0, stream>>>(
        tmp64, w3, b3, a3, bodyA + (size_t)b * 32 * HW, nullptr, 32, H, W, 2);
  }

  const float invHW = 1.f / (float)(H * W);
  const float* sin_[3] = {x, ping, pong};
  float*       sout_[3] = {ping, pong, outp};

  for (int hI = 0; hI < 3; ++hI) {
    // head conv 32->5 (no activation) + global sums for the mean
    conv3x3_k<32, 4, 5, 4, false, true><<<dim3(16, 16, B), 256, 0, stream>>>(
        bodyA, hw[hI], hb[hI], nullptr, ybuf, sums + hI * 20, 5, H, W, 1);
    head_z_k<<<1, 64, 0, stream>>>(sums + hI * 20, cw1[hI], cw2[hI],
                                   zbuf + hI * 20, B, invHW);
    // stage: separable box filters + sharpen + inline softmax combine
    hpass_k<<<dim3(H, B * 3), 256, 0, stream>>>(sin_[hI], h5buf, h15buf, h25buf, H, W);
    combine_k<<<dim3(W / 32, H / 8, B), 256, 0, stream>>>(
        sin_[hI], h5buf, h15buf, h25buf, ybuf, zbuf + hI * 20, sout_[hI], H, W);
  }
}

// Round 4
// 2928.005 us; speedup vs baseline: 1.0688x; 1.0688x over previous
//
#include <hip/hip_runtime.h>
#include <hip/hip_bf16.h>

// ---------------------------------------------------------------------------
// DeepConvWeigthNet on MI355X, fp32, round 2 (2nd resubmit — broker timeouts).
//   conv1(3->32)+PReLU -> bodyA
//   per batch: conv2(32->64)+PReLU -> tmp64 ; conv3(64->32)+PReLU -> bodyA
//   fused head conv (32->15, all 3 heads) -> ybuf (+ per-(b,head,c) sums)
//   head_z: z = sigmoid(ca2 @ relu(ca1 @ mean)) for all 12 (b,head)
//   3x stage_k: fully fused separable box filters + sharpen + inline softmax
// Weights are read via wave-uniform (scalar) loads -> no LDS weight traffic.
// Workspace: bodyA 128 MB | region2 64 MB (tmp64 / ybuf-60) | tail. ~192.3 MB.
// ping/pong alias bodyA (dead after head conv).
// ---------------------------------------------------------------------------

__global__ void zero_k(float* __restrict__ p, int n) {
  int i = blockIdx.x * blockDim.x + threadIdx.x;
  if (i < n) p[i] = 0.f;
}

// Direct 3x3 conv (cross-correlation, zero pad 1), NCHW.
// Block 256 = 32x8; thread computes PY vertical pixels x COB output channels.
// Weights/bias/alpha read with uniform addresses -> scalar loads (no LDS).
template<int CIN, int ICB, int COB, int PY, bool PRELU>
__global__ __launch_bounds__(256)
void conv3x3_k(const float* __restrict__ in, const float* __restrict__ wgt,
               const float* __restrict__ bias, const float* __restrict__ alpha_p,
               float* __restrict__ out, int Cout, int H, int W, int nOcG)
{
  constexpr int TH = 8 * PY;
  constexpr int ROWE = 34;
  __shared__ float s_in[ICB][TH + 2][ROWE];

  const int tid = threadIdx.x;
  const int tx = tid & 31, ty = tid >> 5;
  const int g = blockIdx.z % nOcG, b = blockIdx.z / nOcG;
  const int x0 = blockIdx.x * 32, y0 = blockIdx.y * TH;
  const int oc0 = g * COB;
  const float* inb = in + (size_t)b * CIN * H * W;

  float acc[PY][COB];
#pragma unroll
  for (int p = 0; p < PY; ++p)
#pragma unroll
    for (int o = 0; o < COB; ++o) acc[p][o] = 0.f;

  const int yb = ty * PY;

#pragma unroll 1
  for (int ic0 = 0; ic0 < CIN; ic0 += ICB) {
    constexpr int TILE = ICB * (TH + 2) * ROWE;
    for (int idx = tid; idx < TILE; idx += 256) {
      int icl = idx / ((TH + 2) * ROWE);
      int rem = idx - icl * ((TH + 2) * ROWE);
      int yy = rem / ROWE;
      int xx = rem - yy * ROWE;
      int gy = y0 + yy - 1, gx = x0 + xx - 1;
      float v = 0.f;
      if ((unsigned)gy < (unsigned)H && (unsigned)gx < (unsigned)W)
        v = inb[(size_t)(ic0 + icl) * H * W + (size_t)gy * W + gx];
      s_in[icl][yy][xx] = v;
    }
    __syncthreads();

#pragma unroll 1
    for (int icl = 0; icl < ICB; ++icl) {
      float iv[PY + 2][3];
#pragma unroll
      for (int j = 0; j < PY + 2; ++j)
#pragma unroll
        for (int kx = 0; kx < 3; ++kx)
          iv[j][kx] = s_in[icl][yb + j][tx + kx];
      const float* wb = wgt + ((size_t)oc0 * CIN + (ic0 + icl)) * 9;
#pragma unroll
      for (int o = 0; o < COB; ++o) {
        const float* wp = wb + (size_t)o * CIN * 9;   // uniform -> s_load
        float w9[9];
#pragma unroll
        for (int k = 0; k < 9; ++k) w9[k] = wp[k];
#pragma unroll
        for (int p = 0; p < PY; ++p)
#pragma unroll
          for (int ky = 0; ky < 3; ++ky)
#pragma unroll
            for (int kx = 0; kx < 3; ++kx)
              acc[p][o] = fmaf(iv[p + ky][kx], w9[ky * 3 + kx], acc[p][o]);
      }
    }
    __syncthreads();
  }

  float alpha = 0.f;
  if constexpr (PRELU) alpha = alpha_p[0];

#pragma unroll
  for (int o = 0; o < COB; ++o) {
    const float bv = bias[oc0 + o];
#pragma unroll
    for (int p = 0; p < PY; ++p) {
      const int gy = y0 + yb + p, gx = x0 + tx;
      if (gy < H && gx < W) {
        float v = acc[p][o] + bv;
        if constexpr (PRELU) v = (v > 0.f) ? v : alpha * v;
        out[(((size_t)b * Cout + oc0 + o) * H + gy) * W + gx] = v;
      }
    }
  }
}

// Fused head conv: 32 -> 15 (3 heads x 5 channels), + global sums via atomics.
// y layout: plane ((b*3 + head)*5 + c). sums layout: b*15 + head*5 + c.
__global__ __launch_bounds__(256)
void headconv_k(const float* __restrict__ body,
                const float* __restrict__ hw0, const float* __restrict__ hw1,
                const float* __restrict__ hw2,
                const float* __restrict__ hb0, const float* __restrict__ hb1,
                const float* __restrict__ hb2,
                float* __restrict__ y, float* __restrict__ sums, int H, int W)
{
  constexpr int ICB = 4, PY = 4, TH = 32, ROWE = 34;
  __shared__ float s_in[ICB][TH + 2][ROWE];

  const int tid = threadIdx.x;
  const int tx = tid & 31, ty = tid >> 5;
  const int b = blockIdx.z;
  const int x0 = blockIdx.x * 32, y0 = blockIdx.y * TH;
  const float* inb = body + (size_t)b * 32 * H * W;

  float acc[PY][15];
#pragma unroll
  for (int p = 0; p < PY; ++p)
#pragma unroll
    for (int o = 0; o < 15; ++o) acc[p][o] = 0.f;

  const int yb = ty * PY;

#pragma unroll 1
  for (int ic0 = 0; ic0 < 32; ic0 += ICB) {
    constexpr int TILE = ICB * (TH + 2) * ROWE;
    for (int idx = tid; idx < TILE; idx += 256) {
      int icl = idx / ((TH + 2) * ROWE);
      int rem = idx - icl * ((TH + 2) * ROWE);
      int yy = rem / ROWE;
      int xx = rem - yy * ROWE;
      int gy = y0 + yy - 1, gx = x0 + xx - 1;
      float v = 0.f;
      if ((unsigned)gy < (unsigned)H && (unsigned)gx < (unsigned)W)
        v = inb[(size_t)(ic0 + icl) * H * W + (size_t)gy * W + gx];
      s_in[icl][yy][xx] = v;
    }
    __syncthreads();

#pragma unroll 1
    for (int icl = 0; icl < ICB; ++icl) {
      float iv[PY + 2][3];
#pragma unroll
      for (int j = 0; j < PY + 2; ++j)
#pragma unroll
        for (int kx = 0; kx < 3; ++kx)
          iv[j][kx] = s_in[icl][yb + j][tx + kx];
      const int ic = ic0 + icl;
#pragma unroll
      for (int o = 0; o < 15; ++o) {
        const float* hwp = (o < 5) ? hw0 : (o < 10) ? hw1 : hw2;
        const int c = o - (o < 5 ? 0 : o < 10 ? 5 : 10);
        const float* wp = hwp + ((size_t)c * 32 + ic) * 9;   // uniform
        float w9[9];
#pragma unroll
        for (int k = 0; k < 9; ++k) w9[k] = wp[k];
#pragma unroll
        for (int p = 0; p < PY; ++p)
#pragma unroll
          for (int ky = 0; ky < 3; ++ky)
#pragma unroll
            for (int kx = 0; kx < 3; ++kx)
              acc[p][o] = fmaf(iv[p + ky][kx], w9[ky * 3 + kx], acc[p][o]);
      }
    }
    __syncthreads();
  }

  const size_t HW = (size_t)H * W;
#pragma unroll
  for (int o = 0; o < 15; ++o) {
    const int head = (o < 5) ? 0 : (o < 10) ? 1 : 2;
    const int c = o - head * 5;
    const float bv = (head == 0 ? hb0 : head == 1 ? hb1 : hb2)[c];
    float partial = 0.f;
#pragma unroll
    for (int p = 0; p < PY; ++p) {
      const int gy = y0 + yb + p, gx = x0 + tx;
      float v = acc[p][o] + bv;
      y[((size_t)(b * 3 + head) * 5 + c) * HW + (size_t)gy * W + gx] = v;
      partial += v;
    }
#pragma unroll
    for (int s = 32; s > 0; s >>= 1) partial += __shfl_down(partial, s, 64);
    if ((tid & 63) == 0) atomicAdd(&sums[b * 15 + o], partial);
  }
}

// z = sigmoid(ca2 @ relu(ca1 @ mean)) for all 12 (b,head) pairs.
__global__ void head_z_k(const float* __restrict__ sums,
                         const float* __restrict__ c1a, const float* __restrict__ c2a,
                         const float* __restrict__ c1b, const float* __restrict__ c2b,
                         const float* __restrict__ c1c, const float* __restrict__ c2c,
                         float* __restrict__ z, int B, float invHW)
{
  int t = threadIdx.x;
  if (t >= B * 3) return;
  int b = t / 3, h = t - b * 3;
  const float* w1 = (h == 0) ? c1a : (h == 1) ? c1b : c1c;
  const float* w2 = (h == 0) ? c2a : (h == 1) ? c2b : c2c;
  float m[5], tt[5];
#pragma unroll
  for (int i = 0; i < 5; ++i) m[i] = sums[b * 15 + h * 5 + i] * invHW;
#pragma unroll
  for (int o = 0; o < 5; ++o) {
    float s = 0.f;
#pragma unroll
    for (int i = 0; i < 5; ++i) s = fmaf(w1[o * 5 + i], m[i], s);
    tt[o] = (s > 0.f) ? s : 0.f;
  }
#pragma unroll
  for (int o = 0; o < 5; ++o) {
    float s = 0.f;
#pragma unroll
    for (int i = 0; i < 5; ++i) s = fmaf(w2[o * 5 + i], tt[i], s);
    z[b * 15 + h * 5 + o] = 1.f / (1.f + expf(-s));
  }
}

// Fully fused stage: per 32x32 tile, per channel: stage x (56x56 with halo-12),
// horizontal box sums (5/15/25) in LDS, vertical sliding sums, sharpen,
// inline channel softmax of y*z (computed once, reused for 3 channels).
__global__ __launch_bounds__(256)
void stage_k(const float* __restrict__ xs, const float* __restrict__ y,
             const float* __restrict__ z, float* __restrict__ out,
             int hI, int H, int W)
{
  __shared__ float sx[56][56];
  __shared__ float sh5[56][32], sh15[56][32], sh25[56][32];

  const int tid = threadIdx.x;
  const int tx = tid & 31, tyg = tid >> 5;      // col, row-group (4 rows each)
  const int b = blockIdx.z;
  const int x0 = blockIdx.x * 32, y0 = blockIdx.y * 32;
  const size_t HW = (size_t)H * W;

  // --- per-pixel softmax weights (shared across the 3 image channels) ---
  const float z0 = z[b * 15 + hI * 5 + 0], z1 = z[b * 15 + hI * 5 + 1],
              z2 = z[b * 15 + hI * 5 + 2], z3 = z[b * 15 + hI * 5 + 3],
              z4 = z[b * 15 + hI * 5 + 4];
  const float* yb_ = y + (size_t)(b * 3 + hI) * 5 * HW;
  float hwt[4][5];
#pragma unroll
  for (int p = 0; p < 4; ++p) {
    const size_t pix = (size_t)(y0 + tyg * 4 + p) * W + (x0 + tx);
    float sv[5];
    sv[0] = yb_[0 * HW + pix] * z0;
    sv[1] = yb_[1 * HW + pix] * z1;
    sv[2] = yb_[2 * HW + pix] * z2;
    sv[3] = yb_[3 * HW + pix] * z3;
    sv[4] = yb_[4 * HW + pix] * z4;
    float mx = fmaxf(fmaxf(fmaxf(sv[0], sv[1]), fmaxf(sv[2], sv[3])), sv[4]);
    float se = 0.f;
#pragma unroll
    for (int c = 0; c < 5; ++c) { sv[c] = __expf(sv[c] - mx); se += sv[c]; }
    const float inv = 1.f / se;
#pragma unroll
    for (int c = 0; c < 5; ++c) hwt[p][c] = sv[c] * inv;
  }

#pragma unroll 1
  for (int ch = 0; ch < 3; ++ch) {
    const size_t plane = (size_t)(b * 3 + ch) * HW;
    const float* xp = xs + plane;
    __syncthreads();   // previous channel's LDS fully consumed
    // stage 56x56 input tile (zero OOB)
    for (int t = tid; t < 56 * 56; t += 256) {
      int r = t / 56, c = t - r * 56;
      int gy = y0 + r - 12, gx = x0 + c - 12;
      sx[r][c] = ((unsigned)gy < (unsigned)H && (unsigned)gx < (unsigned)W)
                 ? xp[(size_t)gy * W + gx] : 0.f;
    }
    __syncthreads();
    // horizontal box sums at the 32 out-columns, all 56 rows
    for (int t = tid; t < 56 * 32; t += 256) {
      int r = t >> 5, j = t & 31;
      float s5 = 0.f;
#pragma unroll
      for (int d = -2; d <= 2; ++d) s5 += sx[r][j + 12 + d];
      float s15 = s5;
#pragma unroll
      for (int d = 3; d <= 7; ++d) s15 += sx[r][j + 12 + d] + sx[r][j + 12 - d];
      float s25 = s15;
#pragma unroll
      for (int d = 8; d <= 12; ++d) s25 += sx[r][j + 12 + d] + sx[r][j + 12 - d];
      sh5[r][j] = s5; sh15[r][j] = s15; sh25[r][j] = s25;
    }
    __syncthreads();
    // vertical sliding sums + sharpen + weighted combine
    const int hb = 12 + tyg * 4;
    float v5 = 0.f, v15 = 0.f, v25 = 0.f;
#pragma unroll
    for (int d = -2; d <= 2; ++d) v5 += sh5[hb + d][tx];
#pragma unroll
    for (int d = -7; d <= 7; ++d) v15 += sh15[hb + d][tx];
#pragma unroll
    for (int d = -12; d <= 12; ++d) v25 += sh25[hb + d][tx];
#pragma unroll
    for (int p = 0; p < 4; ++p) {
      const int yo = tyg * 4 + p;
      const float ctr = sx[12 + yo][12 + tx];
      const float sharp = 5.f * ctr - sx[11 + yo][12 + tx] - sx[13 + yo][12 + tx]
                                    - sx[12 + yo][11 + tx] - sx[12 + yo][13 + tx];
      const float res = hwt[p][0] * sharp
                      + hwt[p][1] * ctr
                      + hwt[p][2] * (v5  * (1.f / 25.f))
                      + hwt[p][3] * (v15 * (1.f / 225.f))
                      + hwt[p][4] * (v25 * (1.f / 625.f));
      out[plane + (size_t)(y0 + yo) * W + (x0 + tx)] = res;
      if (p < 3) {
        v5  += sh5 [hb + p + 3][tx] - sh5 [hb + p - 2][tx];
        v15 += sh15[hb + p + 8][tx] - sh15[hb + p - 7][tx];
        v25 += sh25[hb + p + 13][tx] - sh25[hb + p - 12][tx];
      }
    }
  }
}

extern "C" void kernel_launch(void* const* d_in, const int* in_sizes, int n_in,
                              void* d_out, int out_size, void* d_ws, size_t ws_size,
                              hipStream_t stream)
{
  const float* x   = (const float*)d_in[0];
  const float* w1  = (const float*)d_in[1];
  const float* b1  = (const float*)d_in[2];
  const float* a1  = (const float*)d_in[3];
  const float* w2  = (const float*)d_in[4];
  const float* b2  = (const float*)d_in[5];
  const float* a2  = (const float*)d_in[6];
  const float* w3  = (const float*)d_in[7];
  const float* b3  = (const float*)d_in[8];
  const float* a3  = (const float*)d_in[9];
  const float* hw[3]  = {(const float*)d_in[10], (const float*)d_in[14], (const float*)d_in[18]};
  const float* hb[3]  = {(const float*)d_in[11], (const float*)d_in[15], (const float*)d_in[19]};
  const float* cw1[3] = {(const float*)d_in[12], (const float*)d_in[16], (const float*)d_in[20]};
  const float* cw2[3] = {(const float*)d_in[13], (const float*)d_in[17], (const float*)d_in[21]};
  float* outp = (float*)d_out;

  const int B = 4, H = 512, W = 512;
  const size_t HW = (size_t)H * W;
  const size_t PB = HW * sizeof(float);   // 1 MiB plane

  // Workspace (~192.3 MB):
  //   bodyA: planes [0,128)   (conv1/conv3 out; after headconv dead ->
  //                            ping = planes [0,12), pong = planes [12,24))
  //   region2: planes [128,192): tmp64 (per-batch conv2 out, 64 planes),
  //                              later ybuf (60 planes)
  //   tail: sums(64 f) + z(64 f)
  char* ws = (char*)d_ws;
  float* bodyA = (float*)ws;
  float* tmp64 = (float*)(ws + 128 * PB);
  float* ybuf  = tmp64;
  float* ping  = bodyA;
  float* pong  = (float*)(ws + 12 * PB);
  float* sums  = (float*)(ws + 192 * PB);
  float* zbuf  = sums + 64;

  zero_k<<<1, 64, 0, stream>>>(sums, 60);

  // conv1: 3->32 + PReLU, full batch. TH=16.
  conv3x3_k<3, 3, 16, 2, true><<<dim3(16, 32, B * 2), 256, 0, stream>>>(
      x, w1, b1, a1, bodyA, 32, H, W, 2);

  // conv2 (32->64) + conv3 (64->32) per batch through tmp64
  for (int b = 0; b < B; ++b) {
    conv3x3_k<32, 4, 16, 4, true><<<dim3(16, 16, 4), 256, 0, stream>>>(
        bodyA + (size_t)b * 32 * HW, w2, b2, a2, tmp64, 64, H, W, 4);
    conv3x3_k<64, 4, 8, 4, true><<<dim3(16, 16, 4), 256, 0, stream>>>(
        tmp64, w3, b3, a3, bodyA + (size_t)b * 32 * HW, 32, H, W, 4);
  }

  // fused head conv: 32 -> 15 (3 heads), plus global sums
  headconv_k<<<dim3(16, 16, B), 256, 0, stream>>>(
      bodyA, hw[0], hw[1], hw[2], hb[0], hb[1], hb[2], ybuf, sums, H, W);

  const float invHW = 1.f / (float)(H * W);
  head_z_k<<<1, 64, 0, stream>>>(sums, cw1[0], cw2[0], cw1[1], cw2[1],
                                 cw1[2], cw2[2], zbuf, B, invHW);

  // 3 fused stages (bodyA is dead now; ping/pong alias it)
  const float* sin_[3]  = {x, ping, pong};
  float*       sout_[3] = {ping, pong, outp};
  for (int hI = 0; hI < 3; ++hI) {
    stage_k<<<dim3(16, 16, B), 256, 0, stream>>>(
        sin_[hI], ybuf, zbuf, sout_[hI], hI, H, W);
  }
}

// Round 6
// 509.329 us; speedup vs baseline: 6.1444x; 5.7488x over previous
//
#include <hip/hip_runtime.h>

// ---------------------------------------------------------------------------
// DeepConvWeigthNet on MI355X — round 3: MFMA (bf16) conv path.
//   prep_k: transpose/cast all conv weights into per-lane MFMA A-frag layout
//   conv1_k: 3->32, K=3 zero-padded into one mfma 16x16x32 slot, out bf16 icmin
//   mconv_k<KC,MT,..>: 3x3 conv as 9 shifted GEMMs, mfma_f32_16x16x32_bf16
//     conv2: K=32 (KC=1), M=64 (MT=4);  conv3: K=64 (KC=2), M=32 (MT=2)
//     head : K=32, M=16 (15 used) -> y planes fp32 + global sums
//   head_z_k, stage_k: unchanged from round 2 (fp32, verified).
// Layouts: activations bf16 ic-minor [y][x][ic]; LDS tiles pad-40/72 shorts
// per pixel with involution chunk-XOR swizzle (write & read sides).
// Workspace ~168 MB: body1 67 (later y-planes alias) | t64 33.5 (later
// ping/pong alias) | body3 67 | tail (Wt, sums, z).
// ---------------------------------------------------------------------------

typedef __attribute__((ext_vector_type(8))) short short8v;
typedef __attribute__((ext_vector_type(4))) short short4v;
typedef __attribute__((ext_vector_type(4))) float f32x4;

__device__ inline short f2bf(float f) {
  unsigned u = __builtin_bit_cast(unsigned, f);
  unsigned r = (u + 0x7fffu + ((u >> 16) & 1u)) >> 16;
  return (short)r;
}

__global__ void zero_k(float* __restrict__ p, int n) {
  int i = blockIdx.x * blockDim.x + threadIdx.x;
  if (i < n) p[i] = 0.f;
}

// Weight prep: fp32 -> bf16, per-lane MFMA A-frag layout.
// A-frag (16x16x32): lane l supplies A[m = l&15][k = (l>>4)*8 + j], j=0..7.
__global__ void prep_k(const float* __restrict__ w1, const float* __restrict__ w2,
                       const float* __restrict__ w3,
                       const float* __restrict__ hw0, const float* __restrict__ hw1,
                       const float* __restrict__ hw2,
                       const float* __restrict__ hb0, const float* __restrict__ hb1,
                       const float* __restrict__ hb2,
                       short* __restrict__ wt2, short* __restrict__ wt3,
                       short* __restrict__ wth, short* __restrict__ wtc1,
                       float* __restrict__ hbp)
{
  const int N0 = 18432, N1 = 18432, N2 = 4608, N3 = 9216;
  for (int idx = blockIdx.x * 256 + threadIdx.x; idx < N0 + N1 + N2 + N3 + 16;
       idx += gridDim.x * 256) {
    if (idx < N0) {                       // Wt2: [tap][mt4][lane][8]
      int t = idx, j = t & 7, l = (t >> 3) & 63, mt = (t >> 9) & 3, tap = t >> 11;
      int oc = mt * 16 + (l & 15), k = ((l >> 4) << 3) + j;
      wt2[t] = f2bf(w2[(oc * 32 + k) * 9 + tap]);
    } else if (idx < N0 + N1) {           // Wt3: [tap][mt2][kc2][lane][8]
      int t = idx - N0, j = t & 7, l = (t >> 3) & 63, kc = (t >> 9) & 1,
          mt = (t >> 10) & 1, tap = t >> 11;
      int oc = mt * 16 + (l & 15), ic = kc * 32 + ((l >> 4) << 3) + j;
      wt3[t] = f2bf(w3[(oc * 64 + ic) * 9 + tap]);
    } else if (idx < N0 + N1 + N2) {      // WtH: [tap][lane][8], oc15 = 0
      int t = idx - N0 - N1, j = t & 7, l = (t >> 3) & 63, tap = t >> 9;
      int oc = l & 15, ic = ((l >> 4) << 3) + j;
      float v = 0.f;
      if (oc < 15) {
        const float* hw = (oc < 5) ? hw0 : (oc < 10) ? hw1 : hw2;
        v = hw[((oc % 5) * 32 + ic) * 9 + tap];
      }
      wth[t] = f2bf(v);
    } else if (idx < N0 + N1 + N2 + N3) { // WtC1: [tap][mt2][lane][8], k>=3 = 0
      int t = idx - N0 - N1 - N2, j = t & 7, l = (t >> 3) & 63,
          mt = (t >> 9) & 1, tap = t >> 10;
      int oc = mt * 16 + (l & 15), k = ((l >> 4) << 3) + j;
      wtc1[t] = f2bf((k < 3) ? w1[(oc * 3 + k) * 9 + tap] : 0.f);
    } else {                              // hbp[16]
      int oc = idx - N0 - N1 - N2 - N3;
      float v = 0.f;
      if (oc < 15) v = ((oc < 5) ? hb0 : (oc < 10) ? hb1 : hb2)[oc % 5];
      hbp[oc] = v;
    }
  }
}

// conv1: 3->32, fp32 planar in -> bf16 ic-minor out. K=3 in one MFMA slot.
__global__ __launch_bounds__(256)
void conv1_k(const float* __restrict__ x, const short* __restrict__ wt,
             const float* __restrict__ bias, const float* __restrict__ alpha_p,
             short* __restrict__ outb, int H, int W)
{
  __shared__ short tile[340 * 4];
  const int tid = threadIdx.x;
  const int x0 = blockIdx.x * 32, y0 = blockIdx.y * 8, b = blockIdx.z;
  const size_t HW = (size_t)H * W;
  const float* xb = x + (size_t)b * 3 * HW;
  for (int px = tid; px < 340; px += 256) {
    int row = px / 34, col = px - row * 34;
    int gy = y0 - 1 + row, gx = x0 - 1 + col;
    short4v v = {0, 0, 0, 0};
    if ((unsigned)gy < (unsigned)H && (unsigned)gx < (unsigned)W) {
      size_t o = (size_t)gy * W + gx;
      v[0] = f2bf(xb[o]); v[1] = f2bf(xb[HW + o]); v[2] = f2bf(xb[2 * HW + o]);
    }
    *(short4v*)&tile[px * 4] = v;
  }
  __syncthreads();
  const int wid = tid >> 6, g = (tid >> 4) & 3, n = tid & 15;
  f32x4 acc[2][4];
#pragma unroll
  for (int m = 0; m < 2; ++m)
#pragma unroll
    for (int t = 0; t < 4; ++t) acc[m][t] = (f32x4){0.f, 0.f, 0.f, 0.f};
#pragma unroll
  for (int tap = 0; tap < 9; ++tap) {
    const int dy = tap / 3 - 1, dx = tap % 3 - 1;
    short8v A0 = *(const short8v*)(wt + (((tap * 2 + 0) * 64) + (tid & 63)) * 8);
    short8v A1 = *(const short8v*)(wt + (((tap * 2 + 1) * 64) + (tid & 63)) * 8);
#pragma unroll
    for (int nt = 0; nt < 4; ++nt) {
      const int row_l = 1 + 2 * wid + (nt >> 1) + dy;
      const int col_l = 1 + ((nt & 1) << 4) + dx + n;
      short4v s = *(const short4v*)&tile[(row_l * 34 + col_l) * 4];
      short8v B = {0, 0, 0, 0, 0, 0, 0, 0};
      if (g == 0) { B[0] = s[0]; B[1] = s[1]; B[2] = s[2]; }
      acc[0][nt] = __builtin_amdgcn_mfma_f32_16x16x32_bf16(A0, B, acc[0][nt], 0, 0, 0);
      acc[1][nt] = __builtin_amdgcn_mfma_f32_16x16x32_bf16(A1, B, acc[1][nt], 0, 0, 0);
    }
  }
  const float alpha = alpha_p[0];
  float bv[2][4];
#pragma unroll
  for (int mt = 0; mt < 2; ++mt)
#pragma unroll
    for (int r = 0; r < 4; ++r) bv[mt][r] = bias[mt * 16 + g * 4 + r];
  short* ob = outb + (size_t)b * HW * 32;
#pragma unroll
  for (int nt = 0; nt < 4; ++nt) {
    const int py = y0 + 2 * wid + (nt >> 1), px = x0 + ((nt & 1) << 4) + n;
#pragma unroll
    for (int mt = 0; mt < 2; ++mt) {
      short4v o4;
#pragma unroll
      for (int r = 0; r < 4; ++r) {
        float v = acc[mt][nt][r] + bv[mt][r];
        v = v > 0.f ? v : alpha * v;
        o4[r] = f2bf(v);
      }
      *(short4v*)(ob + ((size_t)(py * W + px) * 32 + mt * 16 + g * 4)) = o4;
    }
  }
}

// 3x3 conv as 9 shifted GEMMs. In/out bf16 ic-minor. Block tile 32x8 px,
// 4 waves x 2 rows x (2x16) N-tiles. LDS pad CPAD shorts/px, chunk-XOR swz.
template<int KC, int MT, int CPAD, bool PRELU, bool HEAD>
__global__ __launch_bounds__(256)
void mconv_k(const short* __restrict__ in, const short* __restrict__ wt,
             const float* __restrict__ bias, const float* __restrict__ alpha_p,
             short* __restrict__ outb, float* __restrict__ outy,
             float* __restrict__ sums, int H, int W)
{
  constexpr int CIN = KC * 32, NCH = KC * 4, CMASK = NCH - 1;
  __shared__ short tile[10 * 34 * CPAD];
  __shared__ float hsum[16];
  const int tid = threadIdx.x;
  if (HEAD && tid < 16) hsum[tid] = 0.f;
  const int x0 = blockIdx.x * 32, y0 = blockIdx.y * 8, b = blockIdx.z;
  const size_t HW = (size_t)H * W;
  const short* inb = in + (HEAD ? (size_t)b * HW * CIN : 0);

  for (int idx = tid; idx < 340 * NCH; idx += 256) {
    int q = idx & CMASK, px = idx / NCH;
    int row = px / 34, col = px - row * 34;
    int gy = y0 - 1 + row, gx = x0 - 1 + col;
    short8v v = {0, 0, 0, 0, 0, 0, 0, 0};
    if ((unsigned)gy < (unsigned)H && (unsigned)gx < (unsigned)W)
      v = *(const short8v*)(inb + ((size_t)(gy * W + gx) * CIN + q * 8));
    int slot = q ^ (col & CMASK);
    *(short8v*)&tile[px * CPAD + slot * 8] = v;
  }
  __syncthreads();

  const int wid = tid >> 6, g = (tid >> 4) & 3, n = tid & 15;
  f32x4 acc[MT][4];
#pragma unroll
  for (int m = 0; m < MT; ++m)
#pragma unroll
    for (int t = 0; t < 4; ++t) acc[m][t] = (f32x4){0.f, 0.f, 0.f, 0.f};

#pragma unroll
  for (int tap = 0; tap < 9; ++tap) {
    const int dy = tap / 3 - 1, dx = tap % 3 - 1;
    short8v A[MT][KC];
#pragma unroll
    for (int mt = 0; mt < MT; ++mt)
#pragma unroll
      for (int kc = 0; kc < KC; ++kc)
        A[mt][kc] = *(const short8v*)(wt + ((((tap * MT + mt) * KC + kc) * 64) + (tid & 63)) * 8);
#pragma unroll
    for (int nt = 0; nt < 4; ++nt) {
      const int row_l = 1 + 2 * wid + (nt >> 1) + dy;
      const int col_l = 1 + ((nt & 1) << 4) + dx + n;
      const int base = (row_l * 34 + col_l) * CPAD;
      const int cm = col_l & CMASK;
#pragma unroll
      for (int kc = 0; kc < KC; ++kc) {
        const int slot = (kc * 4 + g) ^ cm;
        short8v B = *(const short8v*)&tile[base + slot * 8];
#pragma unroll
        for (int mt = 0; mt < MT; ++mt)
          acc[mt][nt] = __builtin_amdgcn_mfma_f32_16x16x32_bf16(A[mt][kc], B, acc[mt][nt], 0, 0, 0);
      }
    }
  }

  if constexpr (!HEAD) {
    const float alpha = PRELU ? alpha_p[0] : 0.f;
    float bv[MT][4];
#pragma unroll
    for (int mt = 0; mt < MT; ++mt)
#pragma unroll
      for (int r = 0; r < 4; ++r) bv[mt][r] = bias[mt * 16 + g * 4 + r];
#pragma unroll
    for (int nt = 0; nt < 4; ++nt) {
      const int py = y0 + 2 * wid + (nt >> 1), px = x0 + ((nt & 1) << 4) + n;
#pragma unroll
      for (int mt = 0; mt < MT; ++mt) {
        short4v o4;
#pragma unroll
        for (int r = 0; r < 4; ++r) {
          float v = acc[mt][nt][r] + bv[mt][r];
          if (PRELU) v = v > 0.f ? v : alpha * v;
          o4[r] = f2bf(v);
        }
        *(short4v*)(outb + ((size_t)(py * W + px) * (MT * 16) + mt * 16 + g * 4)) = o4;
      }
    }
  } else {
    float bv[4];
#pragma unroll
    for (int r = 0; r < 4; ++r) bv[r] = bias[g * 4 + r];
    float ps[4] = {0.f, 0.f, 0.f, 0.f};
#pragma unroll
    for (int nt = 0; nt < 4; ++nt) {
      const int py = y0 + 2 * wid + (nt >> 1), px = x0 + ((nt & 1) << 4) + n;
#pragma unroll
      for (int r = 0; r < 4; ++r) {
        const int oc = g * 4 + r;
        float v = acc[0][nt][r] + bv[r];
        if (oc < 15) outy[(size_t)(b * 15 + oc) * HW + (size_t)py * W + px] = v;
        ps[r] += v;
      }
    }
#pragma unroll
    for (int r = 0; r < 4; ++r) {
      float s = ps[r];
#pragma unroll
      for (int m = 1; m < 16; m <<= 1) s += __shfl_xor(s, m, 16);
      if (n == 0 && (g * 4 + r) < 15) atomicAdd(&hsum[g * 4 + r], s);
    }
    __syncthreads();
    if (tid < 15) atomicAdd(&sums[b * 15 + tid], hsum[tid]);
  }
}

// z = sigmoid(ca2 @ relu(ca1 @ mean)) for all 12 (b,head) pairs.
__global__ void head_z_k(const float* __restrict__ sums,
                         const float* __restrict__ c1a, const float* __restrict__ c2a,
                         const float* __restrict__ c1b, const float* __restrict__ c2b,
                         const float* __restrict__ c1c, const float* __restrict__ c2c,
                         float* __restrict__ z, int B, float invHW)
{
  int t = threadIdx.x;
  if (t >= B * 3) return;
  int b = t / 3, h = t - b * 3;
  const float* w1 = (h == 0) ? c1a : (h == 1) ? c1b : c1c;
  const float* w2 = (h == 0) ? c2a : (h == 1) ? c2b : c2c;
  float m[5], tt[5];
#pragma unroll
  for (int i = 0; i < 5; ++i) m[i] = sums[b * 15 + h * 5 + i] * invHW;
#pragma unroll
  for (int o = 0; o < 5; ++o) {
    float s = 0.f;
#pragma unroll
    for (int i = 0; i < 5; ++i) s = fmaf(w1[o * 5 + i], m[i], s);
    tt[o] = (s > 0.f) ? s : 0.f;
  }
#pragma unroll
  for (int o = 0; o < 5; ++o) {
    float s = 0.f;
#pragma unroll
    for (int i = 0; i < 5; ++i) s = fmaf(w2[o * 5 + i], tt[i], s);
    z[b * 15 + h * 5 + o] = 1.f / (1.f + expf(-s));
  }
}

// Fully fused stage (unchanged from round 2, verified).
__global__ __launch_bounds__(256)
void stage_k(const float* __restrict__ xs, const float* __restrict__ y,
             const float* __restrict__ z, float* __restrict__ out,
             int hI, int H, int W)
{
  __shared__ float sx[56][56];
  __shared__ float sh5[56][32], sh15[56][32], sh25[56][32];

  const int tid = threadIdx.x;
  const int tx = tid & 31, tyg = tid >> 5;
  const int b = blockIdx.z;
  const int x0 = blockIdx.x * 32, y0 = blockIdx.y * 32;
  const size_t HW = (size_t)H * W;

  const float z0 = z[b * 15 + hI * 5 + 0], z1 = z[b * 15 + hI * 5 + 1],
              z2 = z[b * 15 + hI * 5 + 2], z3 = z[b * 15 + hI * 5 + 3],
              z4 = z[b * 15 + hI * 5 + 4];
  const float* yb_ = y + (size_t)(b * 15 + hI * 5) * HW;
  float hwt[4][5];
#pragma unroll
  for (int p = 0; p < 4; ++p) {
    const size_t pix = (size_t)(y0 + tyg * 4 + p) * W + (x0 + tx);
    float sv[5];
    sv[0] = yb_[0 * HW + pix] * z0;
    sv[1] = yb_[1 * HW + pix] * z1;
    sv[2] = yb_[2 * HW + pix] * z2;
    sv[3] = yb_[3 * HW + pix] * z3;
    sv[4] = yb_[4 * HW + pix] * z4;
    float mx = fmaxf(fmaxf(fmaxf(sv[0], sv[1]), fmaxf(sv[2], sv[3])), sv[4]);
    float se = 0.f;
#pragma unroll
    for (int c = 0; c < 5; ++c) { sv[c] = __expf(sv[c] - mx); se += sv[c]; }
    const float inv = 1.f / se;
#pragma unroll
    for (int c = 0; c < 5; ++c) hwt[p][c] = sv[c] * inv;
  }

#pragma unroll 1
  for (int ch = 0; ch < 3; ++ch) {
    const size_t plane = (size_t)(b * 3 + ch) * HW;
    const float* xp = xs + plane;
    __syncthreads();
    for (int t = tid; t < 56 * 56; t += 256) {
      int r = t / 56, c = t - r * 56;
      int gy = y0 + r - 12, gx = x0 + c - 12;
      sx[r][c] = ((unsigned)gy < (unsigned)H && (unsigned)gx < (unsigned)W)
                 ? xp[(size_t)gy * W + gx] : 0.f;
    }
    __syncthreads();
    for (int t = tid; t < 56 * 32; t += 256) {
      int r = t >> 5, j = t & 31;
      float s5 = 0.f;
#pragma unroll
      for (int d = -2; d <= 2; ++d) s5 += sx[r][j + 12 + d];
      float s15 = s5;
#pragma unroll
      for (int d = 3; d <= 7; ++d) s15 += sx[r][j + 12 + d] + sx[r][j + 12 - d];
      float s25 = s15;
#pragma unroll
      for (int d = 8; d <= 12; ++d) s25 += sx[r][j + 12 + d] + sx[r][j + 12 - d];
      sh5[r][j] = s5; sh15[r][j] = s15; sh25[r][j] = s25;
    }
    __syncthreads();
    const int hb = 12 + tyg * 4;
    float v5 = 0.f, v15 = 0.f, v25 = 0.f;
#pragma unroll
    for (int d = -2; d <= 2; ++d) v5 += sh5[hb + d][tx];
#pragma unroll
    for (int d = -7; d <= 7; ++d) v15 += sh15[hb + d][tx];
#pragma unroll
    for (int d = -12; d <= 12; ++d) v25 += sh25[hb + d][tx];
#pragma unroll
    for (int p = 0; p < 4; ++p) {
      const int yo = tyg * 4 + p;
      const float ctr = sx[12 + yo][12 + tx];
      const float sharp = 5.f * ctr - sx[11 + yo][12 + tx] - sx[13 + yo][12 + tx]
                                    - sx[12 + yo][11 + tx] - sx[12 + yo][13 + tx];
      const float res = hwt[p][0] * sharp
                      + hwt[p][1] * ctr
                      + hwt[p][2] * (v5  * (1.f / 25.f))
                      + hwt[p][3] * (v15 * (1.f / 225.f))
                      + hwt[p][4] * (v25 * (1.f / 625.f));
      out[plane + (size_t)(y0 + yo) * W + (x0 + tx)] = res;
      if (p < 3) {
        v5  += sh5 [hb + p + 3][tx] - sh5 [hb + p - 2][tx];
        v15 += sh15[hb + p + 8][tx] - sh15[hb + p - 7][tx];
        v25 += sh25[hb + p + 13][tx] - sh25[hb + p - 12][tx];
      }
    }
  }
}

extern "C" void kernel_launch(void* const* d_in, const int* in_sizes, int n_in,
                              void* d_out, int out_size, void* d_ws, size_t ws_size,
                              hipStream_t stream)
{
  const float* x   = (const float*)d_in[0];
  const float* w1  = (const float*)d_in[1];
  const float* b1  = (const float*)d_in[2];
  const float* a1  = (const float*)d_in[3];
  const float* w2  = (const float*)d_in[4];
  const float* b2  = (const float*)d_in[5];
  const float* a2  = (const float*)d_in[6];
  const float* w3  = (const float*)d_in[7];
  const float* b3  = (const float*)d_in[8];
  const float* a3  = (const float*)d_in[9];
  const float* hw[3]  = {(const float*)d_in[10], (const float*)d_in[14], (const float*)d_in[18]};
  const float* hb[3]  = {(const float*)d_in[11], (const float*)d_in[15], (const float*)d_in[19]};
  const float* cw1[3] = {(const float*)d_in[12], (const float*)d_in[16], (const float*)d_in[20]};
  const float* cw2[3] = {(const float*)d_in[13], (const float*)d_in[17], (const float*)d_in[21]};
  float* outp = (float*)d_out;

  const int B = 4, H = 512, W = 512;
  const size_t HW = (size_t)H * W;

  // Workspace map (~168 MB):
  //   [0, 67.1MB)        body1 bf16 [b][y][x][32]; later aliased by ybuf (60MB fp32)
  //   [67.1, 100.7MB)    t64 bf16 1-batch [y][x][64]; later ping(+0)/pong(+16MB)
  //   [100.7, 167.8MB)   body3 bf16 [b][y][x][32]
  //   tail               Wt2|Wt3|WtH|WtC1|hbp|sums|z
  char* ws = (char*)d_ws;
  short* body1 = (short*)ws;
  float* ybuf  = (float*)ws;
  short* t64   = (short*)(ws + 67108864);
  float* ping  = (float*)(ws + 67108864);
  float* pong  = (float*)(ws + 67108864 + 16777216);
  short* body3 = (short*)(ws + 100663296);
  char* tail   = ws + 167772160;
  short* wt2   = (short*)tail;
  short* wt3   = wt2 + 18432;
  short* wth   = wt3 + 18432;
  short* wtc1  = wth + 4608;
  float* hbp   = (float*)(wtc1 + 9216);
  float* sums  = hbp + 16;
  float* zbuf  = sums + 64;

  prep_k<<<32, 256, 0, stream>>>(w1, w2, w3, hw[0], hw[1], hw[2],
                                 hb[0], hb[1], hb[2], wt2, wt3, wth, wtc1, hbp);
  zero_k<<<1, 64, 0, stream>>>(sums, 60);

  // conv1: 3->32 + PReLU (bf16 ic-minor out), full batch
  conv1_k<<<dim3(16, 64, B), 256, 0, stream>>>(x, wtc1, b1, a1, body1, H, W);

  // conv2 (32->64) + conv3 (64->32) per batch through t64
  for (int b = 0; b < B; ++b) {
    mconv_k<1, 4, 40, true, false><<<dim3(16, 64, 1), 256, 0, stream>>>(
        body1 + (size_t)b * HW * 32, wt2, b2, a2, t64, nullptr, nullptr, H, W);
    mconv_k<2, 2, 72, true, false><<<dim3(16, 64, 1), 256, 0, stream>>>(
        t64, wt3, b3, a3, body3 + (size_t)b * HW * 32, nullptr, nullptr, H, W);
  }

  // fused head conv (3 heads, 15 ocs + pad) -> y planes (aliases body1) + sums
  mconv_k<1, 1, 40, false, true><<<dim3(16, 64, B), 256, 0, stream>>>(
      body3, wth, hbp, nullptr, nullptr, ybuf, sums, H, W);

  const float invHW = 1.f / (float)(H * W);
  head_z_k<<<1, 64, 0, stream>>>(sums, cw1[0], cw2[0], cw1[1], cw2[1],
                                 cw1[2], cw2[2], zbuf, B, invHW);

  // 3 fused stages (ping/pong alias t64 region, dead now)
  const float* sin_[3]  = {x, ping, pong};
  float*       sout_[3] = {ping, pong, outp};
  for (int hI = 0; hI < 3; ++hI) {
    stage_k<<<dim3(16, 16, B), 256, 0, stream>>>(
        sin_[hI], ybuf, zbuf, sout_[hI], hI, H, W);
  }
}

// Round 9
// 496.369 us; speedup vs baseline: 6.3048x; 1.0261x over previous
//
#include <hip/hip_runtime.h>

// ---------------------------------------------------------------------------
// DeepConvWeigthNet on MI355X — round 4b (resubmit — broker timeout).
//  vs round 3: (1) A-frags double-buffer-prefetched in registers (no per-tap
//  VMEM stall; head/conv1 fully hoisted); (2) conv2/conv3 as TWO half-batch
//  dispatches each (z=2, 2048 blocks = 8/CU); conv1/head full-batch (z=4);
//  (3) LDS pixel stride CPAD 36/68 shorts (18/34 dwords -> uniform banks).
// Workspace ~134.4 MB (validated bound 201.3 MB):
//   region0 [0, 67.1MB):   body1 bf16 (conv1 out; conv3 out; then ping/pong)
//   region1 [67.1,134.2MB): t64 bf16 2-batch (conv2 out; then y planar fp32)
//   tail    [134.2MB,..):   Wt2|Wt3|WtH|WtC1|hbp|sums|z  (~102 KB)
// ---------------------------------------------------------------------------

typedef __attribute__((ext_vector_type(8))) short short8v;
typedef __attribute__((ext_vector_type(4))) short short4v;
typedef __attribute__((ext_vector_type(4))) float f32x4;

__device__ inline short f2bf(float f) {
  unsigned u = __builtin_bit_cast(unsigned, f);
  unsigned r = (u + 0x7fffu + ((u >> 16) & 1u)) >> 16;
  return (short)r;
}

__global__ void zero_k(float* __restrict__ p, int n) {
  int i = blockIdx.x * blockDim.x + threadIdx.x;
  if (i < n) p[i] = 0.f;
}

// Weight prep: fp32 -> bf16, per-lane MFMA A-frag layout.
// A-frag (16x16x32): lane l supplies A[m = l&15][k = (l>>4)*8 + j], j=0..7.
__global__ void prep_k(const float* __restrict__ w1, const float* __restrict__ w2,
                       const float* __restrict__ w3,
                       const float* __restrict__ hw0, const float* __restrict__ hw1,
                       const float* __restrict__ hw2,
                       const float* __restrict__ hb0, const float* __restrict__ hb1,
                       const float* __restrict__ hb2,
                       short* __restrict__ wt2, short* __restrict__ wt3,
                       short* __restrict__ wth, short* __restrict__ wtc1,
                       float* __restrict__ hbp)
{
  const int N0 = 18432, N1 = 18432, N2 = 4608, N3 = 9216;
  for (int idx = blockIdx.x * 256 + threadIdx.x; idx < N0 + N1 + N2 + N3 + 16;
       idx += gridDim.x * 256) {
    if (idx < N0) {                       // Wt2: [tap][mt4][lane][8]
      int t = idx, j = t & 7, l = (t >> 3) & 63, mt = (t >> 9) & 3, tap = t >> 11;
      int oc = mt * 16 + (l & 15), k = ((l >> 4) << 3) + j;
      wt2[t] = f2bf(w2[(oc * 32 + k) * 9 + tap]);
    } else if (idx < N0 + N1) {           // Wt3: [tap][mt2][kc2][lane][8]
      int t = idx - N0, j = t & 7, l = (t >> 3) & 63, kc = (t >> 9) & 1,
          mt = (t >> 10) & 1, tap = t >> 11;
      int oc = mt * 16 + (l & 15), ic = kc * 32 + ((l >> 4) << 3) + j;
      wt3[t] = f2bf(w3[(oc * 64 + ic) * 9 + tap]);
    } else if (idx < N0 + N1 + N2) {      // WtH: [tap][lane][8], oc15 = 0
      int t = idx - N0 - N1, j = t & 7, l = (t >> 3) & 63, tap = t >> 9;
      int oc = l & 15, ic = ((l >> 4) << 3) + j;
      float v = 0.f;
      if (oc < 15) {
        const float* hw = (oc < 5) ? hw0 : (oc < 10) ? hw1 : hw2;
        v = hw[((oc % 5) * 32 + ic) * 9 + tap];
      }
      wth[t] = f2bf(v);
    } else if (idx < N0 + N1 + N2 + N3) { // WtC1: [tap][mt2][lane][8], k>=3 = 0
      int t = idx - N0 - N1 - N2, j = t & 7, l = (t >> 3) & 63,
          mt = (t >> 9) & 1, tap = t >> 10;
      int oc = mt * 16 + (l & 15), k = ((l >> 4) << 3) + j;
      wtc1[t] = f2bf((k < 3) ? w1[(oc * 3 + k) * 9 + tap] : 0.f);
    } else {                              // hbp[16]
      int oc = idx - N0 - N1 - N2 - N3;
      float v = 0.f;
      if (oc < 15) v = ((oc < 5) ? hb0 : (oc < 10) ? hb1 : hb2)[oc % 5];
      hbp[oc] = v;
    }
  }
}

// conv1: 3->32, fp32 planar in -> bf16 ic-minor out. All 18 A-frags hoisted.
__global__ __launch_bounds__(256)
void conv1_k(const float* __restrict__ x, const short* __restrict__ wt,
             const float* __restrict__ bias, const float* __restrict__ alpha_p,
             short* __restrict__ outb, int H, int W)
{
  __shared__ short tile[340 * 4];
  const int tid = threadIdx.x, lane = tid & 63;
  const int x0 = blockIdx.x * 32, y0 = blockIdx.y * 8, b = blockIdx.z;
  const size_t HW = (size_t)H * W;
  const float* xb = x + (size_t)b * 3 * HW;

  short8v A[9][2];
#pragma unroll
  for (int t = 0; t < 9; ++t) {
    A[t][0] = *(const short8v*)(wt + (((t * 2 + 0) * 64) + lane) * 8);
    A[t][1] = *(const short8v*)(wt + (((t * 2 + 1) * 64) + lane) * 8);
  }

  for (int px = tid; px < 340; px += 256) {
    int row = px / 34, col = px - row * 34;
    int gy = y0 - 1 + row, gx = x0 - 1 + col;
    short4v v = {0, 0, 0, 0};
    if ((unsigned)gy < (unsigned)H && (unsigned)gx < (unsigned)W) {
      size_t o = (size_t)gy * W + gx;
      v[0] = f2bf(xb[o]); v[1] = f2bf(xb[HW + o]); v[2] = f2bf(xb[2 * HW + o]);
    }
    *(short4v*)&tile[px * 4] = v;
  }
  __syncthreads();
  const int wid = tid >> 6, g = (tid >> 4) & 3, n = tid & 15;
  f32x4 acc[2][4];
#pragma unroll
  for (int m = 0; m < 2; ++m)
#pragma unroll
    for (int t = 0; t < 4; ++t) acc[m][t] = (f32x4){0.f, 0.f, 0.f, 0.f};
#pragma unroll
  for (int tap = 0; tap < 9; ++tap) {
    const int dy = tap / 3 - 1, dx = tap % 3 - 1;
#pragma unroll
    for (int nt = 0; nt < 4; ++nt) {
      const int row_l = 1 + 2 * wid + (nt >> 1) + dy;
      const int col_l = 1 + ((nt & 1) << 4) + dx + n;
      short4v s = *(const short4v*)&tile[(row_l * 34 + col_l) * 4];
      short8v B = {0, 0, 0, 0, 0, 0, 0, 0};
      if (g == 0) { B[0] = s[0]; B[1] = s[1]; B[2] = s[2]; }
      acc[0][nt] = __builtin_amdgcn_mfma_f32_16x16x32_bf16(A[tap][0], B, acc[0][nt], 0, 0, 0);
      acc[1][nt] = __builtin_amdgcn_mfma_f32_16x16x32_bf16(A[tap][1], B, acc[1][nt], 0, 0, 0);
    }
  }
  const float alpha = alpha_p[0];
  float bv[2][4];
#pragma unroll
  for (int mt = 0; mt < 2; ++mt)
#pragma unroll
    for (int r = 0; r < 4; ++r) bv[mt][r] = bias[mt * 16 + g * 4 + r];
  short* ob = outb + (size_t)b * HW * 32;
#pragma unroll
  for (int nt = 0; nt < 4; ++nt) {
    const int py = y0 + 2 * wid + (nt >> 1), px = x0 + ((nt & 1) << 4) + n;
#pragma unroll
    for (int mt = 0; mt < 2; ++mt) {
      short4v o4;
#pragma unroll
      for (int r = 0; r < 4; ++r) {
        float v = acc[mt][nt][r] + bv[mt][r];
        v = v > 0.f ? v : alpha * v;
        o4[r] = f2bf(v);
      }
      *(short4v*)(ob + ((size_t)(py * W + px) * 32 + mt * 16 + g * 4)) = o4;
    }
  }
}

// 3x3 conv as 9 shifted GEMMs, batched grid (z = batch-in-dispatch). A-frags
// double-buffer-prefetched in registers. LDS stride CPAD shorts/px, XOR swz.
template<int KC, int MT, int CPAD, bool PRELU, bool HEAD>
__global__ __launch_bounds__(256)
void mconv_k(const short* __restrict__ in, const short* __restrict__ wt,
             const float* __restrict__ bias, const float* __restrict__ alpha_p,
             short* __restrict__ outb, float* __restrict__ outy,
             float* __restrict__ sums, int H, int W)
{
  constexpr int CIN = KC * 32, NCH = KC * 4, CMASK = NCH - 1;
  constexpr int NFRAG = MT * KC;
  __shared__ short tile[10 * 34 * CPAD];
  __shared__ float hsum[16];
  const int tid = threadIdx.x, lane = tid & 63;
  if (HEAD && tid < 16) hsum[tid] = 0.f;
  const int x0 = blockIdx.x * 32, y0 = blockIdx.y * 8, b = blockIdx.z;
  const size_t HW = (size_t)H * W;
  const short* inb = in + (size_t)b * HW * CIN;

  // issue tap-0 A-frag loads first; they complete under the staging loads
  short8v A[2][NFRAG];
#pragma unroll
  for (int f = 0; f < NFRAG; ++f)
    A[0][f] = *(const short8v*)(wt + ((size_t)f * 64 + lane) * 8);

#pragma unroll
  for (int it = 0; it < (340 * NCH + 255) / 256; ++it) {
    int idx = tid + it * 256;
    if (idx < 340 * NCH) {
      int q = idx & CMASK, px = idx / NCH;
      int row = px / 34, col = px - row * 34;
      int gy = y0 - 1 + row, gx = x0 - 1 + col;
      short8v v = {0, 0, 0, 0, 0, 0, 0, 0};
      if ((unsigned)gy < (unsigned)H && (unsigned)gx < (unsigned)W)
        v = *(const short8v*)(inb + ((size_t)(gy * W + gx) * CIN + q * 8));
      int slot = q ^ (col & CMASK);
      *(short8v*)&tile[px * CPAD + slot * 8] = v;
    }
  }
  __syncthreads();

  const int wid = tid >> 6, g = (tid >> 4) & 3, n = tid & 15;
  f32x4 acc[MT][4];
#pragma unroll
  for (int m = 0; m < MT; ++m)
#pragma unroll
    for (int t = 0; t < 4; ++t) acc[m][t] = (f32x4){0.f, 0.f, 0.f, 0.f};

#pragma unroll
  for (int tap = 0; tap < 9; ++tap) {
    if (tap < 8) {
#pragma unroll
      for (int f = 0; f < NFRAG; ++f)
        A[(tap + 1) & 1][f] =
            *(const short8v*)(wt + ((size_t)((tap + 1) * NFRAG + f) * 64 + lane) * 8);
    }
    const int dy = tap / 3 - 1, dx = tap % 3 - 1;
#pragma unroll
    for (int nt = 0; nt < 4; ++nt) {
      const int row_l = 1 + 2 * wid + (nt >> 1) + dy;
      const int col_l = 1 + ((nt & 1) << 4) + dx + n;
      const int base = (row_l * 34 + col_l) * CPAD;
      const int cm = col_l & CMASK;
#pragma unroll
      for (int kc = 0; kc < KC; ++kc) {
        const int slot = (kc * 4 + g) ^ cm;
        short8v B = *(const short8v*)&tile[base + slot * 8];
#pragma unroll
        for (int mt = 0; mt < MT; ++mt)
          acc[mt][nt] = __builtin_amdgcn_mfma_f32_16x16x32_bf16(
              A[tap & 1][mt * KC + kc], B, acc[mt][nt], 0, 0, 0);
      }
    }
  }

  if constexpr (!HEAD) {
    const float alpha = PRELU ? alpha_p[0] : 0.f;
    float bv[MT][4];
#pragma unroll
    for (int mt = 0; mt < MT; ++mt)
#pragma unroll
      for (int r = 0; r < 4; ++r) bv[mt][r] = bias[mt * 16 + g * 4 + r];
    short* ob = outb + (size_t)b * HW * (MT * 16);
#pragma unroll
    for (int nt = 0; nt < 4; ++nt) {
      const int py = y0 + 2 * wid + (nt >> 1), px = x0 + ((nt & 1) << 4) + n;
#pragma unroll
      for (int mt = 0; mt < MT; ++mt) {
        short4v o4;
#pragma unroll
        for (int r = 0; r < 4; ++r) {
          float v = acc[mt][nt][r] + bv[mt][r];
          if (PRELU) v = v > 0.f ? v : alpha * v;
          o4[r] = f2bf(v);
        }
        *(short4v*)(ob + ((size_t)(py * W + px) * (MT * 16) + mt * 16 + g * 4)) = o4;
      }
    }
  } else {
    float bv[4];
#pragma unroll
    for (int r = 0; r < 4; ++r) bv[r] = bias[g * 4 + r];
    float ps[4] = {0.f, 0.f, 0.f, 0.f};
#pragma unroll
    for (int nt = 0; nt < 4; ++nt) {
      const int py = y0 + 2 * wid + (nt >> 1), px = x0 + ((nt & 1) << 4) + n;
#pragma unroll
      for (int r = 0; r < 4; ++r) {
        const int oc = g * 4 + r;
        float v = acc[0][nt][r] + bv[r];
        if (oc < 15) outy[(size_t)(b * 15 + oc) * HW + (size_t)py * W + px] = v;
        ps[r] += v;
      }
    }
#pragma unroll
    for (int r = 0; r < 4; ++r) {
      float s = ps[r];
#pragma unroll
      for (int m = 1; m < 16; m <<= 1) s += __shfl_xor(s, m, 16);
      if (n == 0 && (g * 4 + r) < 15) atomicAdd(&hsum[g * 4 + r], s);
    }
    __syncthreads();
    if (tid < 15) atomicAdd(&sums[b * 15 + tid], hsum[tid]);
  }
}

// z = sigmoid(ca2 @ relu(ca1 @ mean)) for all 12 (b,head) pairs.
__global__ void head_z_k(const float* __restrict__ sums,
                         const float* __restrict__ c1a, const float* __restrict__ c2a,
                         const float* __restrict__ c1b, const float* __restrict__ c2b,
                         const float* __restrict__ c1c, const float* __restrict__ c2c,
                         float* __restrict__ z, int B, float invHW)
{
  int t = threadIdx.x;
  if (t >= B * 3) return;
  int b = t / 3, h = t - b * 3;
  const float* w1 = (h == 0) ? c1a : (h == 1) ? c1b : c1c;
  const float* w2 = (h == 0) ? c2a : (h == 1) ? c2b : c2c;
  float m[5], tt[5];
#pragma unroll
  for (int i = 0; i < 5; ++i) m[i] = sums[b * 15 + h * 5 + i] * invHW;
#pragma unroll
  for (int o = 0; o < 5; ++o) {
    float s = 0.f;
#pragma unroll
    for (int i = 0; i < 5; ++i) s = fmaf(w1[o * 5 + i], m[i], s);
    tt[o] = (s > 0.f) ? s : 0.f;
  }
#pragma unroll
  for (int o = 0; o < 5; ++o) {
    float s = 0.f;
#pragma unroll
    for (int i = 0; i < 5; ++i) s = fmaf(w2[o * 5 + i], tt[i], s);
    z[b * 15 + h * 5 + o] = 1.f / (1.f + expf(-s));
  }
}

// Fully fused stage (unchanged, verified).
__global__ __launch_bounds__(256)
void stage_k(const float* __restrict__ xs, const float* __restrict__ y,
             const float* __restrict__ z, float* __restrict__ out,
             int hI, int H, int W)
{
  __shared__ float sx[56][56];
  __shared__ float sh5[56][32], sh15[56][32], sh25[56][32];

  const int tid = threadIdx.x;
  const int tx = tid & 31, tyg = tid >> 5;
  const int b = blockIdx.z;
  const int x0 = blockIdx.x * 32, y0 = blockIdx.y * 32;
  const size_t HW = (size_t)H * W;

  const float z0 = z[b * 15 + hI * 5 + 0], z1 = z[b * 15 + hI * 5 + 1],
              z2 = z[b * 15 + hI * 5 + 2], z3 = z[b * 15 + hI * 5 + 3],
              z4 = z[b * 15 + hI * 5 + 4];
  const float* yb_ = y + (size_t)(b * 15 + hI * 5) * HW;
  float hwt[4][5];
#pragma unroll
  for (int p = 0; p < 4; ++p) {
    const size_t pix = (size_t)(y0 + tyg * 4 + p) * W + (x0 + tx);
    float sv[5];
    sv[0] = yb_[0 * HW + pix] * z0;
    sv[1] = yb_[1 * HW + pix] * z1;
    sv[2] = yb_[2 * HW + pix] * z2;
    sv[3] = yb_[3 * HW + pix] * z3;
    sv[4] = yb_[4 * HW + pix] * z4;
    float mx = fmaxf(fmaxf(fmaxf(sv[0], sv[1]), fmaxf(sv[2], sv[3])), sv[4]);
    float se = 0.f;
#pragma unroll
    for (int c = 0; c < 5; ++c) { sv[c] = __expf(sv[c] - mx); se += sv[c]; }
    const float inv = 1.f / se;
#pragma unroll
    for (int c = 0; c < 5; ++c) hwt[p][c] = sv[c] * inv;
  }

#pragma unroll 1
  for (int ch = 0; ch < 3; ++ch) {
    const size_t plane = (size_t)(b * 3 + ch) * HW;
    const float* xp = xs + plane;
    __syncthreads();
    for (int t = tid; t < 56 * 56; t += 256) {
      int r = t / 56, c = t - r * 56;
      int gy = y0 + r - 12, gx = x0 + c - 12;
      sx[r][c] = ((unsigned)gy < (unsigned)H && (unsigned)gx < (unsigned)W)
                 ? xp[(size_t)gy * W + gx] : 0.f;
    }
    __syncthreads();
    for (int t = tid; t < 56 * 32; t += 256) {
      int r = t >> 5, j = t & 31;
      float s5 = 0.f;
#pragma unroll
      for (int d = -2; d <= 2; ++d) s5 += sx[r][j + 12 + d];
      float s15 = s5;
#pragma unroll
      for (int d = 3; d <= 7; ++d) s15 += sx[r][j + 12 + d] + sx[r][j + 12 - d];
      float s25 = s15;
#pragma unroll
      for (int d = 8; d <= 12; ++d) s25 += sx[r][j + 12 + d] + sx[r][j + 12 - d];
      sh5[r][j] = s5; sh15[r][j] = s15; sh25[r][j] = s25;
    }
    __syncthreads();
    const int hb = 12 + tyg * 4;
    float v5 = 0.f, v15 = 0.f, v25 = 0.f;
#pragma unroll
    for (int d = -2; d <= 2; ++d) v5 += sh5[hb + d][tx];
#pragma unroll
    for (int d = -7; d <= 7; ++d) v15 += sh15[hb + d][tx];
#pragma unroll
    for (int d = -12; d <= 12; ++d) v25 += sh25[hb + d][tx];
#pragma unroll
    for (int p = 0; p < 4; ++p) {
      const int yo = tyg * 4 + p;
      const float ctr = sx[12 + yo][12 + tx];
      const float sharp = 5.f * ctr - sx[11 + yo][12 + tx] - sx[13 + yo][12 + tx]
                                    - sx[12 + yo][11 + tx] - sx[12 + yo][13 + tx];
      const float res = hwt[p][0] * sharp
                      + hwt[p][1] * ctr
                      + hwt[p][2] * (v5  * (1.f / 25.f))
                      + hwt[p][3] * (v15 * (1.f / 225.f))
                      + hwt[p][4] * (v25 * (1.f / 625.f));
      out[plane + (size_t)(y0 + yo) * W + (x0 + tx)] = res;
      if (p < 3) {
        v5  += sh5 [hb + p + 3][tx] - sh5 [hb + p - 2][tx];
        v15 += sh15[hb + p + 8][tx] - sh15[hb + p - 7][tx];
        v25 += sh25[hb + p + 13][tx] - sh25[hb + p - 12][tx];
      }
    }
  }
}

extern "C" void kernel_launch(void* const* d_in, const int* in_sizes, int n_in,
                              void* d_out, int out_size, void* d_ws, size_t ws_size,
                              hipStream_t stream)
{
  const float* x   = (const float*)d_in[0];
  const float* w1  = (const float*)d_in[1];
  const float* b1  = (const float*)d_in[2];
  const float* a1  = (const float*)d_in[3];
  const float* w2  = (const float*)d_in[4];
  const float* b2  = (const float*)d_in[5];
  const float* a2  = (const float*)d_in[6];
  const float* w3  = (const float*)d_in[7];
  const float* b3  = (const float*)d_in[8];
  const float* a3  = (const float*)d_in[9];
  const float* hw[3]  = {(const float*)d_in[10], (const float*)d_in[14], (const float*)d_in[18]};
  const float* hb[3]  = {(const float*)d_in[11], (const float*)d_in[15], (const float*)d_in[19]};
  const float* cw1[3] = {(const float*)d_in[12], (const float*)d_in[16], (const float*)d_in[20]};
  const float* cw2[3] = {(const float*)d_in[13], (const float*)d_in[17], (const float*)d_in[21]};
  float* outp = (float*)d_out;

  const int B = 4, H = 512, W = 512;
  const size_t HW = (size_t)H * W;

  // Workspace (~134.4 MB, validated bound 201.3 MB):
  //   region0 [0, 67.1MB):    body1 bf16 [b][pix][32] (conv1 out; conv3 out;
  //                           after head: ping @0, pong @16MB)
  //   region1 [67.1,134.2MB): t64 bf16 2-batch [pix][64] (conv2 half-out;
  //                           after conv3: y planar fp32 60MB)
  //   tail   [134.2MB, ..):   Wt2|Wt3|WtH|WtC1|hbp|sums|z
  char* ws = (char*)d_ws;
  short* body1 = (short*)ws;
  float* ping  = (float*)ws;
  float* pong  = (float*)(ws + 16777216);
  short* t64   = (short*)(ws + 67108864);
  float* ybuf  = (float*)(ws + 67108864);
  char* tail   = ws + 134217728;
  short* wt2   = (short*)tail;
  short* wt3   = wt2 + 18432;
  short* wth   = wt3 + 18432;
  short* wtc1  = wth + 4608;
  float* hbp   = (float*)(wtc1 + 9216);
  float* sums  = hbp + 16;
  float* zbuf  = sums + 64;

  prep_k<<<32, 256, 0, stream>>>(w1, w2, w3, hw[0], hw[1], hw[2],
                                 hb[0], hb[1], hb[2], wt2, wt3, wth, wtc1, hbp);
  zero_k<<<1, 64, 0, stream>>>(sums, 60);

  // conv1: 3->32 + PReLU, full batch, one dispatch
  conv1_k<<<dim3(16, 64, B), 256, 0, stream>>>(x, wtc1, b1, a1, body1, H, W);

  // conv2 (32->64) / conv3 (64->32): two half-batch dispatches each,
  // t64 holds 2 batches (keeps workspace under the validated bound)
  for (int h = 0; h < 2; ++h) {
    mconv_k<1, 4, 36, true, false><<<dim3(16, 64, 2), 256, 0, stream>>>(
        body1 + (size_t)h * 2 * HW * 32, wt2, b2, a2, t64, nullptr, nullptr, H, W);
    mconv_k<2, 2, 68, true, false><<<dim3(16, 64, 2), 256, 0, stream>>>(
        t64, wt3, b3, a3, body1 + (size_t)h * 2 * HW * 32, nullptr, nullptr, H, W);
  }

  // fused head conv (3 heads, 15 ocs) -> y planes (alias region1) + sums
  mconv_k<1, 1, 36, false, true><<<dim3(16, 64, B), 256, 0, stream>>>(
      body1, wth, hbp, nullptr, nullptr, ybuf, sums, H, W);

  const float invHW = 1.f / (float)(H * W);
  head_z_k<<<1, 64, 0, stream>>>(sums, cw1[0], cw2[0], cw1[1], cw2[1],
                                 cw1[2], cw2[2], zbuf, B, invHW);

  // 3 fused stages (ping/pong alias body1, dead after head)
  const float* sin_[3]  = {x, ping, pong};
  float*       sout_[3] = {ping, pong, outp};
  for (int hI = 0; hI < 3; ++hI) {
    stage_k<<<dim3(16, 16, B), 256, 0, stream>>>(
        sin_[hI], ybuf, zbuf, sout_[hI], hI, H, W);
  }
}

// Round 10
// 385.691 us; speedup vs baseline: 8.1140x; 1.2870x over previous
//
#include <hip/hip_runtime.h>

// ---------------------------------------------------------------------------
// DeepConvWeigthNet on MI355X — round 5: kill global-atomic contention.
//  vs round 4b: (1) head conv writes per-block partial sums (no atomics);
//  head_z_k does the 1024-way reduction (12 blocks, coalesced). (2) A-frag
//  prefetch distance 2 (3-buffer rotation). (3) zero_k dropped.
// Workspace ~134.6 MB:
//   region0 [0, 67.1MB):   body1 bf16 (conv1 out; conv3 out; then ping/pong)
//   region1 [67.1,134.2MB): t64 bf16 2-batch (conv2 out; then y planar fp32)
//   tail    [134.2MB,..):   Wt2|Wt3|WtH|WtC1|hbp|z|part  (~350 KB)
// ---------------------------------------------------------------------------

typedef __attribute__((ext_vector_type(8))) short short8v;
typedef __attribute__((ext_vector_type(4))) short short4v;
typedef __attribute__((ext_vector_type(4))) float f32x4;

__device__ inline short f2bf(float f) {
  unsigned u = __builtin_bit_cast(unsigned, f);
  unsigned r = (u + 0x7fffu + ((u >> 16) & 1u)) >> 16;
  return (short)r;
}

// Weight prep: fp32 -> bf16, per-lane MFMA A-frag layout.
// A-frag (16x16x32): lane l supplies A[m = l&15][k = (l>>4)*8 + j], j=0..7.
__global__ void prep_k(const float* __restrict__ w1, const float* __restrict__ w2,
                       const float* __restrict__ w3,
                       const float* __restrict__ hw0, const float* __restrict__ hw1,
                       const float* __restrict__ hw2,
                       const float* __restrict__ hb0, const float* __restrict__ hb1,
                       const float* __restrict__ hb2,
                       short* __restrict__ wt2, short* __restrict__ wt3,
                       short* __restrict__ wth, short* __restrict__ wtc1,
                       float* __restrict__ hbp)
{
  const int N0 = 18432, N1 = 18432, N2 = 4608, N3 = 9216;
  for (int idx = blockIdx.x * 256 + threadIdx.x; idx < N0 + N1 + N2 + N3 + 16;
       idx += gridDim.x * 256) {
    if (idx < N0) {                       // Wt2: [tap][mt4][lane][8]
      int t = idx, j = t & 7, l = (t >> 3) & 63, mt = (t >> 9) & 3, tap = t >> 11;
      int oc = mt * 16 + (l & 15), k = ((l >> 4) << 3) + j;
      wt2[t] = f2bf(w2[(oc * 32 + k) * 9 + tap]);
    } else if (idx < N0 + N1) {           // Wt3: [tap][mt2][kc2][lane][8]
      int t = idx - N0, j = t & 7, l = (t >> 3) & 63, kc = (t >> 9) & 1,
          mt = (t >> 10) & 1, tap = t >> 11;
      int oc = mt * 16 + (l & 15), ic = kc * 32 + ((l >> 4) << 3) + j;
      wt3[t] = f2bf(w3[(oc * 64 + ic) * 9 + tap]);
    } else if (idx < N0 + N1 + N2) {      // WtH: [tap][lane][8], oc15 = 0
      int t = idx - N0 - N1, j = t & 7, l = (t >> 3) & 63, tap = t >> 9;
      int oc = l & 15, ic = ((l >> 4) << 3) + j;
      float v = 0.f;
      if (oc < 15) {
        const float* hw = (oc < 5) ? hw0 : (oc < 10) ? hw1 : hw2;
        v = hw[((oc % 5) * 32 + ic) * 9 + tap];
      }
      wth[t] = f2bf(v);
    } else if (idx < N0 + N1 + N2 + N3) { // WtC1: [tap][mt2][lane][8], k>=3 = 0
      int t = idx - N0 - N1 - N2, j = t & 7, l = (t >> 3) & 63,
          mt = (t >> 9) & 1, tap = t >> 10;
      int oc = mt * 16 + (l & 15), k = ((l >> 4) << 3) + j;
      wtc1[t] = f2bf((k < 3) ? w1[(oc * 3 + k) * 9 + tap] : 0.f);
    } else {                              // hbp[16]
      int oc = idx - N0 - N1 - N2 - N3;
      float v = 0.f;
      if (oc < 15) v = ((oc < 5) ? hb0 : (oc < 10) ? hb1 : hb2)[oc % 5];
      hbp[oc] = v;
    }
  }
}

// conv1: 3->32, fp32 planar in -> bf16 ic-minor out. All 18 A-frags hoisted.
__global__ __launch_bounds__(256)
void conv1_k(const float* __restrict__ x, const short* __restrict__ wt,
             const float* __restrict__ bias, const float* __restrict__ alpha_p,
             short* __restrict__ outb, int H, int W)
{
  __shared__ short tile[340 * 4];
  const int tid = threadIdx.x, lane = tid & 63;
  const int x0 = blockIdx.x * 32, y0 = blockIdx.y * 8, b = blockIdx.z;
  const size_t HW = (size_t)H * W;
  const float* xb = x + (size_t)b * 3 * HW;

  short8v A[9][2];
#pragma unroll
  for (int t = 0; t < 9; ++t) {
    A[t][0] = *(const short8v*)(wt + (((t * 2 + 0) * 64) + lane) * 8);
    A[t][1] = *(const short8v*)(wt + (((t * 2 + 1) * 64) + lane) * 8);
  }

  for (int px = tid; px < 340; px += 256) {
    int row = px / 34, col = px - row * 34;
    int gy = y0 - 1 + row, gx = x0 - 1 + col;
    short4v v = {0, 0, 0, 0};
    if ((unsigned)gy < (unsigned)H && (unsigned)gx < (unsigned)W) {
      size_t o = (size_t)gy * W + gx;
      v[0] = f2bf(xb[o]); v[1] = f2bf(xb[HW + o]); v[2] = f2bf(xb[2 * HW + o]);
    }
    *(short4v*)&tile[px * 4] = v;
  }
  __syncthreads();
  const int wid = tid >> 6, g = (tid >> 4) & 3, n = tid & 15;
  f32x4 acc[2][4];
#pragma unroll
  for (int m = 0; m < 2; ++m)
#pragma unroll
    for (int t = 0; t < 4; ++t) acc[m][t] = (f32x4){0.f, 0.f, 0.f, 0.f};
#pragma unroll
  for (int tap = 0; tap < 9; ++tap) {
    const int dy = tap / 3 - 1, dx = tap % 3 - 1;
#pragma unroll
    for (int nt = 0; nt < 4; ++nt) {
      const int row_l = 1 + 2 * wid + (nt >> 1) + dy;
      const int col_l = 1 + ((nt & 1) << 4) + dx + n;
      short4v s = *(const short4v*)&tile[(row_l * 34 + col_l) * 4];
      short8v B = {0, 0, 0, 0, 0, 0, 0, 0};
      if (g == 0) { B[0] = s[0]; B[1] = s[1]; B[2] = s[2]; }
      acc[0][nt] = __builtin_amdgcn_mfma_f32_16x16x32_bf16(A[tap][0], B, acc[0][nt], 0, 0, 0);
      acc[1][nt] = __builtin_amdgcn_mfma_f32_16x16x32_bf16(A[tap][1], B, acc[1][nt], 0, 0, 0);
    }
  }
  const float alpha = alpha_p[0];
  float bv[2][4];
#pragma unroll
  for (int mt = 0; mt < 2; ++mt)
#pragma unroll
    for (int r = 0; r < 4; ++r) bv[mt][r] = bias[mt * 16 + g * 4 + r];
  short* ob = outb + (size_t)b * HW * 32;
#pragma unroll
  for (int nt = 0; nt < 4; ++nt) {
    const int py = y0 + 2 * wid + (nt >> 1), px = x0 + ((nt & 1) << 4) + n;
#pragma unroll
    for (int mt = 0; mt < 2; ++mt) {
      short4v o4;
#pragma unroll
      for (int r = 0; r < 4; ++r) {
        float v = acc[mt][nt][r] + bv[mt][r];
        v = v > 0.f ? v : alpha * v;
        o4[r] = f2bf(v);
      }
      *(short4v*)(ob + ((size_t)(py * W + px) * 32 + mt * 16 + g * 4)) = o4;
    }
  }
}

// 3x3 conv as 9 shifted GEMMs, batched grid (z = batch-in-dispatch). A-frags
// prefetched distance-2 (3-buffer rotation). LDS stride CPAD shorts/px, swz.
// HEAD: per-block partial sums written non-atomically to part[].
template<int KC, int MT, int CPAD, bool PRELU, bool HEAD>
__global__ __launch_bounds__(256)
void mconv_k(const short* __restrict__ in, const short* __restrict__ wt,
             const float* __restrict__ bias, const float* __restrict__ alpha_p,
             short* __restrict__ outb, float* __restrict__ outy,
             float* __restrict__ part, int H, int W)
{
  constexpr int CIN = KC * 32, NCH = KC * 4, CMASK = NCH - 1;
  constexpr int NFRAG = MT * KC;
  __shared__ short tile[10 * 34 * CPAD];
  __shared__ float hsum[16];
  const int tid = threadIdx.x, lane = tid & 63;
  if (HEAD && tid < 16) hsum[tid] = 0.f;
  const int x0 = blockIdx.x * 32, y0 = blockIdx.y * 8, b = blockIdx.z;
  const size_t HW = (size_t)H * W;
  const short* inb = in + (size_t)b * HW * CIN;

  // prefetch taps 0 and 1 before staging; distance-2 pipeline thereafter
  short8v A[3][NFRAG];
#pragma unroll
  for (int f = 0; f < NFRAG; ++f)
    A[0][f] = *(const short8v*)(wt + ((size_t)f * 64 + lane) * 8);
#pragma unroll
  for (int f = 0; f < NFRAG; ++f)
    A[1][f] = *(const short8v*)(wt + ((size_t)(NFRAG + f) * 64 + lane) * 8);

#pragma unroll
  for (int it = 0; it < (340 * NCH + 255) / 256; ++it) {
    int idx = tid + it * 256;
    if (idx < 340 * NCH) {
      int q = idx & CMASK, px = idx / NCH;
      int row = px / 34, col = px - row * 34;
      int gy = y0 - 1 + row, gx = x0 - 1 + col;
      short8v v = {0, 0, 0, 0, 0, 0, 0, 0};
      if ((unsigned)gy < (unsigned)H && (unsigned)gx < (unsigned)W)
        v = *(const short8v*)(inb + ((size_t)(gy * W + gx) * CIN + q * 8));
      int slot = q ^ (col & CMASK);
      *(short8v*)&tile[px * CPAD + slot * 8] = v;
    }
  }
  __syncthreads();

  const int wid = tid >> 6, g = (tid >> 4) & 3, n = tid & 15;
  f32x4 acc[MT][4];
#pragma unroll
  for (int m = 0; m < MT; ++m)
#pragma unroll
    for (int t = 0; t < 4; ++t) acc[m][t] = (f32x4){0.f, 0.f, 0.f, 0.f};

#pragma unroll
  for (int tap = 0; tap < 9; ++tap) {
    if (tap < 7) {
#pragma unroll
      for (int f = 0; f < NFRAG; ++f)
        A[(tap + 2) % 3][f] =
            *(const short8v*)(wt + ((size_t)((tap + 2) * NFRAG + f) * 64 + lane) * 8);
    }
    const int dy = tap / 3 - 1, dx = tap % 3 - 1;
#pragma unroll
    for (int nt = 0; nt < 4; ++nt) {
      const int row_l = 1 + 2 * wid + (nt >> 1) + dy;
      const int col_l = 1 + ((nt & 1) << 4) + dx + n;
      const int base = (row_l * 34 + col_l) * CPAD;
      const int cm = col_l & CMASK;
#pragma unroll
      for (int kc = 0; kc < KC; ++kc) {
        const int slot = (kc * 4 + g) ^ cm;
        short8v B = *(const short8v*)&tile[base + slot * 8];
#pragma unroll
        for (int mt = 0; mt < MT; ++mt)
          acc[mt][nt] = __builtin_amdgcn_mfma_f32_16x16x32_bf16(
              A[tap % 3][mt * KC + kc], B, acc[mt][nt], 0, 0, 0);
      }
    }
  }

  if constexpr (!HEAD) {
    const float alpha = PRELU ? alpha_p[0] : 0.f;
    float bv[MT][4];
#pragma unroll
    for (int mt = 0; mt < MT; ++mt)
#pragma unroll
      for (int r = 0; r < 4; ++r) bv[mt][r] = bias[mt * 16 + g * 4 + r];
    short* ob = outb + (size_t)b * HW * (MT * 16);
#pragma unroll
    for (int nt = 0; nt < 4; ++nt) {
      const int py = y0 + 2 * wid + (nt >> 1), px = x0 + ((nt & 1) << 4) + n;
#pragma unroll
      for (int mt = 0; mt < MT; ++mt) {
        short4v o4;
#pragma unroll
        for (int r = 0; r < 4; ++r) {
          float v = acc[mt][nt][r] + bv[mt][r];
          if (PRELU) v = v > 0.f ? v : alpha * v;
          o4[r] = f2bf(v);
        }
        *(short4v*)(ob + ((size_t)(py * W + px) * (MT * 16) + mt * 16 + g * 4)) = o4;
      }
    }
  } else {
    float bv[4];
#pragma unroll
    for (int r = 0; r < 4; ++r) bv[r] = bias[g * 4 + r];
    float ps[4] = {0.f, 0.f, 0.f, 0.f};
#pragma unroll
    for (int nt = 0; nt < 4; ++nt) {
      const int py = y0 + 2 * wid + (nt >> 1), px = x0 + ((nt & 1) << 4) + n;
#pragma unroll
      for (int r = 0; r < 4; ++r) {
        const int oc = g * 4 + r;
        float v = acc[0][nt][r] + bv[r];
        if (oc < 15) outy[(size_t)(b * 15 + oc) * HW + (size_t)py * W + px] = v;
        ps[r] += v;
      }
    }
#pragma unroll
    for (int r = 0; r < 4; ++r) {
      float s = ps[r];
#pragma unroll
      for (int m = 1; m < 16; m <<= 1) s += __shfl_xor(s, m, 16);
      if (n == 0 && (g * 4 + r) < 15) atomicAdd(&hsum[g * 4 + r], s);  // LDS only
    }
    __syncthreads();
    // non-atomic per-block partial: part[(b*15+oc)*1024 + blk]
    if (tid < 15)
      part[(size_t)(b * 15 + tid) * 1024 + (blockIdx.y * 16 + blockIdx.x)] = hsum[tid];
  }
}

// Reduce per-block partials -> mean -> z = sigmoid(ca2 @ relu(ca1 @ mean)).
// One block per (b, head) pair; coalesced 1024-float sums.
__global__ __launch_bounds__(256)
void head_z_k(const float* __restrict__ part,
              const float* __restrict__ c1a, const float* __restrict__ c2a,
              const float* __restrict__ c1b, const float* __restrict__ c2b,
              const float* __restrict__ c1c, const float* __restrict__ c2c,
              float* __restrict__ z, float invHW)
{
  __shared__ float red[4];
  __shared__ float mm[5];
  const int tid = threadIdx.x;
  const int b = blockIdx.x / 3, h = blockIdx.x % 3;

#pragma unroll 1
  for (int oc = 0; oc < 5; ++oc) {
    const float* p = part + (size_t)(b * 15 + h * 5 + oc) * 1024;
    float s = 0.f;
#pragma unroll
    for (int i = 0; i < 4; ++i) s += p[tid + i * 256];
#pragma unroll
    for (int m = 1; m < 64; m <<= 1) s += __shfl_xor(s, m, 64);
    if ((tid & 63) == 0) red[tid >> 6] = s;
    __syncthreads();
    if (tid == 0) mm[oc] = (red[0] + red[1] + red[2] + red[3]) * invHW;
    __syncthreads();
  }

  if (tid == 0) {
    const float* w1 = (h == 0) ? c1a : (h == 1) ? c1b : c1c;
    const float* w2 = (h == 0) ? c2a : (h == 1) ? c2b : c2c;
    float tt[5];
#pragma unroll
    for (int o = 0; o < 5; ++o) {
      float s = 0.f;
#pragma unroll
      for (int i = 0; i < 5; ++i) s = fmaf(w1[o * 5 + i], mm[i], s);
      tt[o] = (s > 0.f) ? s : 0.f;
    }
#pragma unroll
    for (int o = 0; o < 5; ++o) {
      float s = 0.f;
#pragma unroll
      for (int i = 0; i < 5; ++i) s = fmaf(w2[o * 5 + i], tt[i], s);
      z[b * 15 + h * 5 + o] = 1.f / (1.f + expf(-s));
    }
  }
}

// Fully fused stage (unchanged, verified).
__global__ __launch_bounds__(256)
void stage_k(const float* __restrict__ xs, const float* __restrict__ y,
             const float* __restrict__ z, float* __restrict__ out,
             int hI, int H, int W)
{
  __shared__ float sx[56][56];
  __shared__ float sh5[56][32], sh15[56][32], sh25[56][32];

  const int tid = threadIdx.x;
  const int tx = tid & 31, tyg = tid >> 5;
  const int b = blockIdx.z;
  const int x0 = blockIdx.x * 32, y0 = blockIdx.y * 32;
  const size_t HW = (size_t)H * W;

  const float z0 = z[b * 15 + hI * 5 + 0], z1 = z[b * 15 + hI * 5 + 1],
              z2 = z[b * 15 + hI * 5 + 2], z3 = z[b * 15 + hI * 5 + 3],
              z4 = z[b * 15 + hI * 5 + 4];
  const float* yb_ = y + (size_t)(b * 15 + hI * 5) * HW;
  float hwt[4][5];
#pragma unroll
  for (int p = 0; p < 4; ++p) {
    const size_t pix = (size_t)(y0 + tyg * 4 + p) * W + (x0 + tx);
    float sv[5];
    sv[0] = yb_[0 * HW + pix] * z0;
    sv[1] = yb_[1 * HW + pix] * z1;
    sv[2] = yb_[2 * HW + pix] * z2;
    sv[3] = yb_[3 * HW + pix] * z3;
    sv[4] = yb_[4 * HW + pix] * z4;
    float mx = fmaxf(fmaxf(fmaxf(sv[0], sv[1]), fmaxf(sv[2], sv[3])), sv[4]);
    float se = 0.f;
#pragma unroll
    for (int c = 0; c < 5; ++c) { sv[c] = __expf(sv[c] - mx); se += sv[c]; }
    const float inv = 1.f / se;
#pragma unroll
    for (int c = 0; c < 5; ++c) hwt[p][c] = sv[c] * inv;
  }

#pragma unroll 1
  for (int ch = 0; ch < 3; ++ch) {
    const size_t plane = (size_t)(b * 3 + ch) * HW;
    const float* xp = xs + plane;
    __syncthreads();
    for (int t = tid; t < 56 * 56; t += 256) {
      int r = t / 56, c = t - r * 56;
      int gy = y0 + r - 12, gx = x0 + c - 12;
      sx[r][c] = ((unsigned)gy < (unsigned)H && (unsigned)gx < (unsigned)W)
                 ? xp[(size_t)gy * W + gx] : 0.f;
    }
    __syncthreads();
    for (int t = tid; t < 56 * 32; t += 256) {
      int r = t >> 5, j = t & 31;
      float s5 = 0.f;
#pragma unroll
      for (int d = -2; d <= 2; ++d) s5 += sx[r][j + 12 + d];
      float s15 = s5;
#pragma unroll
      for (int d = 3; d <= 7; ++d) s15 += sx[r][j + 12 + d] + sx[r][j + 12 - d];
      float s25 = s15;
#pragma unroll
      for (int d = 8; d <= 12; ++d) s25 += sx[r][j + 12 + d] + sx[r][j + 12 - d];
      sh5[r][j] = s5; sh15[r][j] = s15; sh25[r][j] = s25;
    }
    __syncthreads();
    const int hb = 12 + tyg * 4;
    float v5 = 0.f, v15 = 0.f, v25 = 0.f;
#pragma unroll
    for (int d = -2; d <= 2; ++d) v5 += sh5[hb + d][tx];
#pragma unroll
    for (int d = -7; d <= 7; ++d) v15 += sh15[hb + d][tx];
#pragma unroll
    for (int d = -12; d <= 12; ++d) v25 += sh25[hb + d][tx];
#pragma unroll
    for (int p = 0; p < 4; ++p) {
      const int yo = tyg * 4 + p;
      const float ctr = sx[12 + yo][12 + tx];
      const float sharp = 5.f * ctr - sx[11 + yo][12 + tx] - sx[13 + yo][12 + tx]
                                    - sx[12 + yo][11 + tx] - sx[12 + yo][13 + tx];
      const float res = hwt[p][0] * sharp
                      + hwt[p][1] * ctr
                      + hwt[p][2] * (v5  * (1.f / 25.f))
                      + hwt[p][3] * (v15 * (1.f / 225.f))
                      + hwt[p][4] * (v25 * (1.f / 625.f));
      out[plane + (size_t)(y0 + yo) * W + (x0 + tx)] = res;
      if (p < 3) {
        v5  += sh5 [hb + p + 3][tx] - sh5 [hb + p - 2][tx];
        v15 += sh15[hb + p + 8][tx] - sh15[hb + p - 7][tx];
        v25 += sh25[hb + p + 13][tx] - sh25[hb + p - 12][tx];
      }
    }
  }
}

extern "C" void kernel_launch(void* const* d_in, const int* in_sizes, int n_in,
                              void* d_out, int out_size, void* d_ws, size_t ws_size,
                              hipStream_t stream)
{
  const float* x   = (const float*)d_in[0];
  const float* w1  = (const float*)d_in[1];
  const float* b1  = (const float*)d_in[2];
  const float* a1  = (const float*)d_in[3];
  const float* w2  = (const float*)d_in[4];
  const float* b2  = (const float*)d_in[5];
  const float* a2  = (const float*)d_in[6];
  const float* w3  = (const float*)d_in[7];
  const float* b3  = (const float*)d_in[8];
  const float* a3  = (const float*)d_in[9];
  const float* hw[3]  = {(const float*)d_in[10], (const float*)d_in[14], (const float*)d_in[18]};
  const float* hb[3]  = {(const float*)d_in[11], (const float*)d_in[15], (const float*)d_in[19]};
  const float* cw1[3] = {(const float*)d_in[12], (const float*)d_in[16], (const float*)d_in[20]};
  const float* cw2[3] = {(const float*)d_in[13], (const float*)d_in[17], (const float*)d_in[21]};
  float* outp = (float*)d_out;

  const int B = 4, H = 512, W = 512;
  const size_t HW = (size_t)H * W;

  // Workspace (~134.6 MB):
  //   region0 [0, 67.1MB):    body1 bf16 [b][pix][32] (conv1 out; conv3 out;
  //                           after head: ping @0, pong @16MB)
  //   region1 [67.1,134.2MB): t64 bf16 2-batch [pix][64] (conv2 half-out;
  //                           after conv3: y planar fp32 60MB)
  //   tail   [134.2MB, ..):   Wt2|Wt3|WtH|WtC1|hbp|z|part
  char* ws = (char*)d_ws;
  short* body1 = (short*)ws;
  float* ping  = (float*)ws;
  float* pong  = (float*)(ws + 16777216);
  short* t64   = (short*)(ws + 67108864);
  float* ybuf  = (float*)(ws + 67108864);
  char* tail   = ws + 134217728;
  short* wt2   = (short*)tail;
  short* wt3   = wt2 + 18432;
  short* wth   = wt3 + 18432;
  short* wtc1  = wth + 4608;
  float* hbp   = (float*)(wtc1 + 9216);
  float* zbuf  = hbp + 16;
  float* part  = zbuf + 64;          // 60 * 1024 floats = 240 KB

  prep_k<<<32, 256, 0, stream>>>(w1, w2, w3, hw[0], hw[1], hw[2],
                                 hb[0], hb[1], hb[2], wt2, wt3, wth, wtc1, hbp);

  // conv1: 3->32 + PReLU, full batch, one dispatch
  conv1_k<<<dim3(16, 64, B), 256, 0, stream>>>(x, wtc1, b1, a1, body1, H, W);

  // conv2 (32->64) / conv3 (64->32): two half-batch dispatches each
  for (int h = 0; h < 2; ++h) {
    mconv_k<1, 4, 36, true, false><<<dim3(16, 64, 2), 256, 0, stream>>>(
        body1 + (size_t)h * 2 * HW * 32, wt2, b2, a2, t64, nullptr, nullptr, H, W);
    mconv_k<2, 2, 68, true, false><<<dim3(16, 64, 2), 256, 0, stream>>>(
        t64, wt3, b3, a3, body1 + (size_t)h * 2 * HW * 32, nullptr, nullptr, H, W);
  }

  // fused head conv (3 heads, 15 ocs) -> y planes (alias region1) + partials
  mconv_k<1, 1, 36, false, true><<<dim3(16, 64, B), 256, 0, stream>>>(
      body1, wth, hbp, nullptr, nullptr, ybuf, part, H, W);

  const float invHW = 1.f / (float)(H * W);
  head_z_k<<<12, 256, 0, stream>>>(part, cw1[0], cw2[0], cw1[1], cw2[1],
                                   cw1[2], cw2[2], zbuf, invHW);

  // 3 fused stages (ping/pong alias body1, dead after head)
  const float* sin_[3]  = {x, ping, pong};
  float*       sout_[3] = {ping, pong, outp};
  for (int hI = 0; hI < 3; ++hI) {
    stage_k<<<dim3(16, 16, B), 256, 0, stream>>>(
        sin_[hI], ybuf, zbuf, sout_[hI], hI, H, W);
  }
}